// Round 1
// baseline (540.146 us; speedup 1.0000x reference)
//
#include <hip/hip_runtime.h>
#include <hip/hip_bf16.h>

typedef __bf16 bf16x8 __attribute__((ext_vector_type(8)));
typedef float f32x4 __attribute__((ext_vector_type(4)));
typedef unsigned short u16;

#define EMB 512
#define FF 2048
#define MTOT 4096
#define SEQ 2048

__device__ __forceinline__ u16 f2b(float f) {
  return __builtin_bit_cast(u16, (__bf16)f);
}

// ---------------- transpose fp32 [K,N] -> bf16 [N,K] ----------------
__global__ void transpose_to_bf16(const float* __restrict__ src, u16* __restrict__ dst,
                                  int K, int N) {
  __shared__ float t[32][33];
  int n0 = blockIdx.x * 32, k0 = blockIdx.y * 32;
  int tx = threadIdx.x, ty = threadIdx.y;
#pragma unroll
  for (int i = 0; i < 4; i++)
    t[ty + i * 8][tx] = src[(size_t)(k0 + ty + i * 8) * N + n0 + tx];
  __syncthreads();
#pragma unroll
  for (int i = 0; i < 4; i++)
    dst[(size_t)(n0 + ty + i * 8) * K + k0 + tx] = f2b(t[tx][ty + i * 8]);
}

// ---------------- fp32 -> bf16 elementwise (8 elems/thread) ----------------
__global__ void cvt_bf16(const float* __restrict__ src, u16* __restrict__ dst) {
  size_t i = (size_t)(blockIdx.x * 256 + threadIdx.x) * 8;
  float4 a = *(const float4*)(src + i);
  float4 b = *(const float4*)(src + i + 4);
  uint4 u;
  u.x = f2b(a.x) | ((unsigned)f2b(a.y) << 16);
  u.y = f2b(a.z) | ((unsigned)f2b(a.w) << 16);
  u.z = f2b(b.x) | ((unsigned)f2b(b.y) << 16);
  u.w = f2b(b.z) | ((unsigned)f2b(b.w) << 16);
  *(uint4*)(dst + i) = u;
}

// ---------------- bias concat (512-chunks) ----------------
__global__ void concat3(const float* a, const float* b, const float* c, float* dst) {
  int i = blockIdx.x * 256 + threadIdx.x;
  if (i < 512) dst[i] = a[i];
  else if (i < 1024) dst[i] = b[i - 512];
  else if (c) dst[i] = c[i - 1024];
}

// ---------------- bf16 GEMM: C[M,Nd] = A[M,K] @ Bt[Nd,K]^T + bias (+res,+gelu) ----
// 128x128 tile, 4 waves (2x2 of 64x64), BK=32, mfma_f32_16x16x32_bf16.
template <bool OUTB, bool OUTF, bool RES, bool GELU_>
__global__ __launch_bounds__(256) void gemm_bt(
    const u16* __restrict__ A, const u16* __restrict__ Bt,
    const float* __restrict__ bias, const float* __restrict__ resid,
    u16* __restrict__ outb, float* __restrict__ outf, int K, int Nd) {
  __shared__ u16 As[128 * 40];  // stride 40 elems = 80B: 16B-aligned rows, bank-spread
  __shared__ u16 Bs[128 * 40];
  int tid = threadIdx.x;
  int lane = tid & 63, w = tid >> 6;
  int g = lane >> 4, li = lane & 15;
  int wr = w >> 1, wc = w & 1;
  int m0 = blockIdx.x * 128, n0 = blockIdx.y * 128;
  f32x4 acc[4][4] = {};
  for (int k0 = 0; k0 < K; k0 += 32) {
    __syncthreads();
#pragma unroll
    for (int r = 0; r < 2; r++) {
      int e = (r * 256 + tid) * 8;
      int row = e >> 5, col = e & 31;
      *(uint4*)&As[row * 40 + col] = *(const uint4*)&A[(size_t)(m0 + row) * K + k0 + col];
      *(uint4*)&Bs[row * 40 + col] = *(const uint4*)&Bt[(size_t)(n0 + row) * K + k0 + col];
    }
    __syncthreads();
    bf16x8 af[4], bfr[4];
#pragma unroll
    for (int i = 0; i < 4; i++)
      af[i] = *(const bf16x8*)&As[(wr * 64 + i * 16 + li) * 40 + g * 8];
#pragma unroll
    for (int i = 0; i < 4; i++)
      bfr[i] = *(const bf16x8*)&Bs[(wc * 64 + i * 16 + li) * 40 + g * 8];
#pragma unroll
    for (int mi = 0; mi < 4; mi++)
#pragma unroll
      for (int ni = 0; ni < 4; ni++)
        acc[mi][ni] = __builtin_amdgcn_mfma_f32_16x16x32_bf16(af[mi], bfr[ni], acc[mi][ni], 0, 0, 0);
  }
#pragma unroll
  for (int mi = 0; mi < 4; mi++)
#pragma unroll
    for (int ni = 0; ni < 4; ni++) {
      int gn = n0 + wc * 64 + ni * 16 + li;
      float bv = bias[gn];
#pragma unroll
      for (int r = 0; r < 4; r++) {
        int gm = m0 + wr * 64 + mi * 16 + g * 4 + r;
        float v = acc[mi][ni][r] + bv;
        if (RES) v += resid[(size_t)gm * Nd + gn];
        if (GELU_) v = 0.5f * v * (1.0f + erff(v * 0.70710678118654752f));
        if (OUTF) outf[(size_t)gm * Nd + gn] = v;
        if (OUTB) outb[(size_t)gm * Nd + gn] = f2b(v);
      }
    }
}

// ---------------- flash attention, bf16 MFMA ----------------
// grid (B*H, SEQ/64), 4 waves; wave = 16 queries; KV tiles of 32.
template <bool CAUSAL>
__global__ __launch_bounds__(256) void attn_fwd(
    const u16* __restrict__ Q, const u16* __restrict__ Kp,
    const u16* __restrict__ Vp, u16* __restrict__ O, int qs, int kvs) {
  __shared__ u16 Ks[32 * 72];       // K tile [key][d], stride 72
  __shared__ u16 Vt[64 * 40];       // V^T tile [d][key], stride 40
  __shared__ u16 Ps[4 * 16 * 40];   // per-wave P scratch [q][key]
  int tid = threadIdx.x;
  int lane = tid & 63, w = tid >> 6;
  int g = lane >> 4, li = lane & 15;
  int b = blockIdx.x >> 3, h = blockIdx.x & 7;
  int qb = blockIdx.y * 64;
  int q_lo = qb + w * 16;
  const u16* Qh = Q + (size_t)b * SEQ * qs + h * 64;
  const u16* Kh = Kp + (size_t)b * SEQ * kvs + h * 64;
  const u16* Vh = Vp + (size_t)b * SEQ * kvs + h * 64;
  bf16x8 qa[2];
#pragma unroll
  for (int ks = 0; ks < 2; ks++)
    qa[ks] = *(const bf16x8*)&Qh[(size_t)(q_lo + li) * qs + ks * 32 + g * 8];
  f32x4 o[4] = {};
  float mrow[4], lrow[4];
#pragma unroll
  for (int r = 0; r < 4; r++) { mrow[r] = -1e30f; lrow[r] = 0.f; }
  int kv_end = CAUSAL ? (qb + 64) : SEQ;
  for (int kv0 = 0; kv0 < kv_end; kv0 += 32) {
    __syncthreads();
    {  // cooperative staging: K as-is, V transposed
      int key = tid >> 3, d0 = (tid & 7) * 8;
      *(uint4*)&Ks[key * 72 + d0] = *(const uint4*)&Kh[(size_t)(kv0 + key) * kvs + d0];
      uint4 vv = *(const uint4*)&Vh[(size_t)(kv0 + key) * kvs + d0];
      Vt[(d0 + 0) * 40 + key] = (u16)(vv.x & 0xffff);
      Vt[(d0 + 1) * 40 + key] = (u16)(vv.x >> 16);
      Vt[(d0 + 2) * 40 + key] = (u16)(vv.y & 0xffff);
      Vt[(d0 + 3) * 40 + key] = (u16)(vv.y >> 16);
      Vt[(d0 + 4) * 40 + key] = (u16)(vv.z & 0xffff);
      Vt[(d0 + 5) * 40 + key] = (u16)(vv.z >> 16);
      Vt[(d0 + 6) * 40 + key] = (u16)(vv.w & 0xffff);
      Vt[(d0 + 7) * 40 + key] = (u16)(vv.w >> 16);
    }
    __syncthreads();
    if (!CAUSAL || kv0 <= q_lo + 15) {
      f32x4 S[2] = {};
#pragma unroll
      for (int nt = 0; nt < 2; nt++)
#pragma unroll
        for (int ks = 0; ks < 2; ks++) {
          bf16x8 kb = *(const bf16x8*)&Ks[(nt * 16 + li) * 72 + ks * 32 + g * 8];
          S[nt] = __builtin_amdgcn_mfma_f32_16x16x32_bf16(qa[ks], kb, S[nt], 0, 0, 0);
        }
#pragma unroll
      for (int nt = 0; nt < 2; nt++)
#pragma unroll
        for (int r = 0; r < 4; r++) {
          float s = S[nt][r] * 0.125f;  // 1/sqrt(64)
          if (CAUSAL) {
            int key = kv0 + nt * 16 + li;
            int qq = q_lo + g * 4 + r;
            if (key > qq) s = -1e30f;
          }
          S[nt][r] = s;
        }
      float pm[4], csc[4], rs[4];
#pragma unroll
      for (int r = 0; r < 4; r++) pm[r] = fmaxf(S[0][r], S[1][r]);
#pragma unroll
      for (int d = 1; d < 16; d <<= 1)
#pragma unroll
        for (int r = 0; r < 4; r++) pm[r] = fmaxf(pm[r], __shfl_xor(pm[r], d, 64));
#pragma unroll
      for (int r = 0; r < 4; r++) {
        float nm = fmaxf(mrow[r], pm[r]);
        csc[r] = __expf(mrow[r] - nm);
        float act = (nm <= -1e29f) ? 0.f : 1.f;  // fully-masked-row guard
        S[0][r] = act * __expf(S[0][r] - nm);
        S[1][r] = act * __expf(S[1][r] - nm);
        rs[r] = S[0][r] + S[1][r];
        mrow[r] = nm;
      }
#pragma unroll
      for (int d = 1; d < 16; d <<= 1)
#pragma unroll
        for (int r = 0; r < 4; r++) rs[r] += __shfl_xor(rs[r], d, 64);
#pragma unroll
      for (int r = 0; r < 4; r++) lrow[r] = lrow[r] * csc[r] + rs[r];
#pragma unroll
      for (int nt = 0; nt < 4; nt++)
#pragma unroll
        for (int r = 0; r < 4; r++) o[nt][r] *= csc[r];
      // P -> LDS (D-layout) -> A-fragment layout
      u16* pw = &Ps[w * 640];
#pragma unroll
      for (int nt = 0; nt < 2; nt++)
#pragma unroll
        for (int r = 0; r < 4; r++)
          pw[(g * 4 + r) * 40 + nt * 16 + li] = f2b(S[nt][r]);
      bf16x8 pa = *(const bf16x8*)&pw[li * 40 + g * 8];
#pragma unroll
      for (int nt = 0; nt < 4; nt++) {
        bf16x8 vb = *(const bf16x8*)&Vt[(nt * 16 + li) * 40 + g * 8];
        o[nt] = __builtin_amdgcn_mfma_f32_16x16x32_bf16(pa, vb, o[nt], 0, 0, 0);
      }
    }
  }
  float inv[4];
#pragma unroll
  for (int r = 0; r < 4; r++) inv[r] = 1.0f / lrow[r];
#pragma unroll
  for (int nt = 0; nt < 4; nt++)
#pragma unroll
    for (int r = 0; r < 4; r++)
      O[(size_t)b * SEQ * EMB + (size_t)(q_lo + g * 4 + r) * EMB + h * 64 + nt * 16 + li] =
          f2b(o[nt][r] * inv[r]);
}

// ---------------- LayerNorm (one wave per 512-row), fp32 + optional bf16 out ----
__global__ __launch_bounds__(256) void ln_fused(
    const float* __restrict__ in, const float* __restrict__ gamma,
    const float* __restrict__ beta, float* __restrict__ outf, u16* __restrict__ outb) {
  int row = blockIdx.x * 4 + (threadIdx.x >> 6);
  int lane = threadIdx.x & 63;
  const float* p = in + (size_t)row * EMB + lane * 8;
  float v[8];
  *(float4*)&v[0] = *(const float4*)p;
  *(float4*)&v[4] = *(const float4*)(p + 4);
  float s = 0.f, q = 0.f;
#pragma unroll
  for (int j = 0; j < 8; j++) { s += v[j]; q += v[j] * v[j]; }
#pragma unroll
  for (int d = 1; d < 64; d <<= 1) {
    s += __shfl_xor(s, d, 64);
    q += __shfl_xor(q, d, 64);
  }
  float mu = s * (1.0f / EMB);
  float var = q * (1.0f / EMB) - mu * mu;
  float rsig = rsqrtf(var + 1e-5f);
  float gg[8], bb[8];
  *(float4*)&gg[0] = *(const float4*)(gamma + lane * 8);
  *(float4*)&gg[4] = *(const float4*)(gamma + lane * 8 + 4);
  *(float4*)&bb[0] = *(const float4*)(beta + lane * 8);
  *(float4*)&bb[4] = *(const float4*)(beta + lane * 8 + 4);
  float o[8];
#pragma unroll
  for (int j = 0; j < 8; j++) o[j] = (v[j] - mu) * rsig * gg[j] + bb[j];
  float* po = outf + (size_t)row * EMB + lane * 8;
  *(float4*)po = *(float4*)&o[0];
  *(float4*)(po + 4) = *(float4*)&o[4];
  if (outb) {
    uint4 u;
    u.x = f2b(o[0]) | ((unsigned)f2b(o[1]) << 16);
    u.y = f2b(o[2]) | ((unsigned)f2b(o[3]) << 16);
    u.z = f2b(o[4]) | ((unsigned)f2b(o[5]) << 16);
    u.w = f2b(o[6]) | ((unsigned)f2b(o[7]) << 16);
    *(uint4*)(outb + (size_t)row * EMB + lane * 8) = u;
  }
}

extern "C" void kernel_launch(void* const* d_in, const int* in_sizes, int n_in,
                              void* d_out, int out_size, void* d_ws, size_t ws_size,
                              hipStream_t stream) {
  const float* x     = (const float*)d_in[0];
  const float* enc   = (const float*)d_in[1];
  const float* sa_wq = (const float*)d_in[2];
  const float* sa_bq = (const float*)d_in[3];
  const float* sa_wk = (const float*)d_in[4];
  const float* sa_bk = (const float*)d_in[5];
  const float* sa_wv = (const float*)d_in[6];
  const float* sa_bv = (const float*)d_in[7];
  const float* sa_wo = (const float*)d_in[8];
  const float* sa_bo = (const float*)d_in[9];
  const float* ca_wq = (const float*)d_in[10];
  const float* ca_bq = (const float*)d_in[11];
  const float* ca_wk = (const float*)d_in[12];
  const float* ca_bk = (const float*)d_in[13];
  const float* ca_wv = (const float*)d_in[14];
  const float* ca_bv = (const float*)d_in[15];
  const float* ca_wo = (const float*)d_in[16];
  const float* ca_bo = (const float*)d_in[17];
  const float* ln1_g = (const float*)d_in[18];
  const float* ln1_b = (const float*)d_in[19];
  const float* ln2_g = (const float*)d_in[20];
  const float* ln2_b = (const float*)d_in[21];
  const float* ln3_g = (const float*)d_in[22];
  const float* ln3_b = (const float*)d_in[23];
  const float* ff_w1 = (const float*)d_in[24];
  const float* ff_b1 = (const float*)d_in[25];
  const float* ff_w2 = (const float*)d_in[26];
  const float* ff_b2 = (const float*)d_in[27];

  char* ws = (char*)d_ws;
  size_t off = 0;
  auto alloc = [&](size_t bytes) {
    void* p = ws + off;
    off = (off + bytes + 255) & ~(size_t)255;
    return p;
  };
  u16* qkvT_sa  = (u16*)alloc((size_t)1536 * EMB * 2);
  u16* oT_sa    = (u16*)alloc((size_t)EMB * EMB * 2);
  u16* qT_ca    = (u16*)alloc((size_t)EMB * EMB * 2);
  u16* kvT_ca   = (u16*)alloc((size_t)1024 * EMB * 2);
  u16* oT_ca    = (u16*)alloc((size_t)EMB * EMB * 2);
  u16* w1T      = (u16*)alloc((size_t)FF * EMB * 2);
  u16* w2T      = (u16*)alloc((size_t)EMB * FF * 2);
  float* bqkv_sa = (float*)alloc(1536 * 4);
  float* bkv_ca  = (float*)alloc(1024 * 4);
  u16* xb    = (u16*)alloc((size_t)MTOT * EMB * 2);
  u16* encb  = (u16*)alloc((size_t)MTOT * EMB * 2);
  u16* qkv   = (u16*)alloc((size_t)MTOT * 1536 * 2);
  u16* attnb = (u16*)alloc((size_t)MTOT * EMB * 2);
  float* t0  = (float*)alloc((size_t)MTOT * EMB * 4);
  float* x1  = (float*)alloc((size_t)MTOT * EMB * 4);
  u16* x1b   = (u16*)alloc((size_t)MTOT * EMB * 2);
  float* x2  = (float*)alloc((size_t)MTOT * EMB * 4);
  u16* x2b   = (u16*)alloc((size_t)MTOT * EMB * 2);
  u16* hbuf  = (u16*)alloc((size_t)MTOT * FF * 2);
  // aliases (lifetimes disjoint): qca reuses xb; kvca reuses qkv
  u16* qca  = xb;   // xb dead after SA-QKV gemm; qca written later
  u16* kvca = qkv;  // qkv dead after SA attention

  dim3 tb(32, 8);
  transpose_to_bf16<<<dim3(16, 16), tb, 0, stream>>>(sa_wq, qkvT_sa, EMB, EMB);
  transpose_to_bf16<<<dim3(16, 16), tb, 0, stream>>>(sa_wk, qkvT_sa + 512 * EMB, EMB, EMB);
  transpose_to_bf16<<<dim3(16, 16), tb, 0, stream>>>(sa_wv, qkvT_sa + 1024 * EMB, EMB, EMB);
  transpose_to_bf16<<<dim3(16, 16), tb, 0, stream>>>(sa_wo, oT_sa, EMB, EMB);
  transpose_to_bf16<<<dim3(16, 16), tb, 0, stream>>>(ca_wq, qT_ca, EMB, EMB);
  transpose_to_bf16<<<dim3(16, 16), tb, 0, stream>>>(ca_wk, kvT_ca, EMB, EMB);
  transpose_to_bf16<<<dim3(16, 16), tb, 0, stream>>>(ca_wv, kvT_ca + 512 * EMB, EMB, EMB);
  transpose_to_bf16<<<dim3(16, 16), tb, 0, stream>>>(ca_wo, oT_ca, EMB, EMB);
  transpose_to_bf16<<<dim3(64, 16), tb, 0, stream>>>(ff_w1, w1T, EMB, FF);
  transpose_to_bf16<<<dim3(16, 64), tb, 0, stream>>>(ff_w2, w2T, FF, EMB);
  concat3<<<6, 256, 0, stream>>>(sa_bq, sa_bk, sa_bv, bqkv_sa);
  concat3<<<4, 256, 0, stream>>>(ca_bk, ca_bv, nullptr, bkv_ca);
  cvt_bf16<<<1024, 256, 0, stream>>>(x, xb);
  cvt_bf16<<<1024, 256, 0, stream>>>(enc, encb);

  // ---- self-attention block ----
  gemm_bt<true, false, false, false><<<dim3(32, 12), 256, 0, stream>>>(
      xb, qkvT_sa, bqkv_sa, nullptr, qkv, nullptr, EMB, 1536);
  attn_fwd<true><<<dim3(16, 32), 256, 0, stream>>>(qkv, qkv + 512, qkv + 1024, attnb, 1536, 1536);
  gemm_bt<false, true, true, false><<<dim3(32, 4), 256, 0, stream>>>(
      attnb, oT_sa, sa_bo, x, nullptr, t0, EMB, EMB);
  ln_fused<<<1024, 256, 0, stream>>>(t0, ln1_g, ln1_b, x1, x1b);

  // ---- cross-attention block ----
  gemm_bt<true, false, false, false><<<dim3(32, 4), 256, 0, stream>>>(
      x1b, qT_ca, ca_bq, nullptr, qca, nullptr, EMB, EMB);
  gemm_bt<true, false, false, false><<<dim3(32, 8), 256, 0, stream>>>(
      encb, kvT_ca, bkv_ca, nullptr, kvca, nullptr, EMB, 1024);
  attn_fwd<false><<<dim3(16, 32), 256, 0, stream>>>(qca, kvca, kvca + 512, attnb, EMB, 1024);
  gemm_bt<false, true, true, false><<<dim3(32, 4), 256, 0, stream>>>(
      attnb, oT_ca, ca_bo, x1, nullptr, t0, EMB, EMB);
  ln_fused<<<1024, 256, 0, stream>>>(t0, ln2_g, ln2_b, x2, x2b);

  // ---- FFN block ----
  gemm_bt<true, false, false, true><<<dim3(32, 16), 256, 0, stream>>>(
      x2b, w1T, ff_b1, nullptr, hbuf, nullptr, EMB, FF);
  gemm_bt<false, true, true, false><<<dim3(32, 4), 256, 0, stream>>>(
      hbuf, w2T, ff_b2, x2, nullptr, t0, FF, EMB);
  ln_fused<<<1024, 256, 0, stream>>>(t0, ln3_g, ln3_b, (float*)d_out, nullptr);
}

// Round 2
// 379.414 us; speedup vs baseline: 1.4236x; 1.4236x over previous
//
#include <hip/hip_runtime.h>
#include <hip/hip_bf16.h>

typedef __bf16 bf16x8 __attribute__((ext_vector_type(8)));
typedef float f32x4 __attribute__((ext_vector_type(4)));
typedef unsigned short u16;

#define EMB 512
#define FF 2048
#define MTOT 4096
#define SEQ 2048

__device__ __forceinline__ u16 f2b(float f) {
  return __builtin_bit_cast(u16, (__bf16)f);
}

__device__ __forceinline__ int swz64(int row) { return ((row >> 3) ^ row) & 7; }

__device__ __forceinline__ void gload16(const u16* g, u16* l) {
  __builtin_amdgcn_global_load_lds(
      (const __attribute__((address_space(1))) unsigned int*)g,
      (__attribute__((address_space(3))) unsigned int*)l, 16, 0, 0);
}

// ---------------- fused prep: 10 weight transposes + 2 cvt + 2 bias concats ----
__global__ __launch_bounds__(256) void prep_all(
    const float* s0, const float* s1, const float* s2, const float* s3,
    const float* s4, const float* s5, const float* s6, const float* s7,
    const float* s8, const float* s9,
    u16* d0, u16* d1, u16* d2, u16* d3, u16* d4,
    u16* d5, u16* d6, u16* d7, u16* d8, u16* d9,
    const float* x, u16* xb, const float* enc, u16* encb,
    const float* bq1, const float* bk1, const float* bv1, float* bqkv,
    const float* bk2, const float* bv2, float* bkv) {
  int z = blockIdx.z, bx = blockIdx.x, by = blockIdx.y;
  int tid = threadIdx.x;
  if (z >= 10) {  // fp32 -> bf16 cvt of x / enc, 2048 elems per block
    int fb = by * 64 + bx;
    const float* src = (z == 10) ? x : enc;
    u16* dst = (z == 10) ? xb : encb;
    size_t base = (size_t)fb * 2048 + tid * 8;
    float4 a = *(const float4*)(src + base);
    float4 b = *(const float4*)(src + base + 4);
    uint4 u;
    u.x = f2b(a.x) | ((unsigned)f2b(a.y) << 16);
    u.y = f2b(a.z) | ((unsigned)f2b(a.w) << 16);
    u.z = f2b(b.x) | ((unsigned)f2b(b.y) << 16);
    u.w = f2b(b.z) | ((unsigned)f2b(b.w) << 16);
    *(uint4*)(dst + base) = u;
    return;
  }
  if (z == 0 && bx == 16 && by == 0) {
    for (int i = tid; i < 1536; i += 256)
      bqkv[i] = (i < 512) ? bq1[i] : (i < 1024 ? bk1[i - 512] : bv1[i - 1024]);
    return;
  }
  if (z == 1 && bx == 16 && by == 0) {
    for (int i = tid; i < 1024; i += 256)
      bkv[i] = (i < 512) ? bk2[i] : bv2[i - 512];
    return;
  }
  const float* src; u16* dst; int K, N;
  switch (z) {
    case 0: src = s0; dst = d0; K = 512; N = 512; break;
    case 1: src = s1; dst = d1; K = 512; N = 512; break;
    case 2: src = s2; dst = d2; K = 512; N = 512; break;
    case 3: src = s3; dst = d3; K = 512; N = 512; break;
    case 4: src = s4; dst = d4; K = 512; N = 512; break;
    case 5: src = s5; dst = d5; K = 512; N = 512; break;
    case 6: src = s6; dst = d6; K = 512; N = 512; break;
    case 7: src = s7; dst = d7; K = 512; N = 512; break;
    case 8: src = s8; dst = d8; K = 512; N = 2048; break;
    default: src = s9; dst = d9; K = 2048; N = 512; break;
  }
  int ntl, ktl;
  if (z == 9) { ktl = bx; ntl = by; } else { ntl = bx; ktl = by; }
  if (ntl * 32 >= N || ktl * 32 >= K) return;
  __shared__ float t[32][33];
  int tx = tid & 31, ty = tid >> 5;
  int n0 = ntl * 32, k0 = ktl * 32;
#pragma unroll
  for (int i = 0; i < 4; i++)
    t[ty + i * 8][tx] = src[(size_t)(k0 + ty + i * 8) * N + n0 + tx];
  __syncthreads();
#pragma unroll
  for (int i = 0; i < 4; i++)
    dst[(size_t)(n0 + ty + i * 8) * K + k0 + tx] = f2b(t[tx][ty + i * 8]);
}

// ---------------- bf16 GEMM (m97 structure): global_load_lds + swizzled LDS ----
// C[M,Nd] = A[M,K] @ Bt[Nd,K]^T + bias (+res,+gelu). 128x128 tile, 4 waves, BK=32.
template <bool OUTB, bool OUTF, bool RES, bool GELU_>
__global__ __launch_bounds__(256) void gemm_bt(
    const u16* __restrict__ A, const u16* __restrict__ Bt,
    const float* __restrict__ bias, const float* __restrict__ resid,
    u16* __restrict__ outb, float* __restrict__ outf, int K, int Nd) {
  __shared__ u16 As[128 * 32];
  __shared__ u16 Bs[128 * 32];
  int tid = threadIdx.x;
  int lane = tid & 63, w = tid >> 6;
  int g = lane >> 4, li = lane & 15;
  int wr = w >> 1, wc = w & 1;
  int m0 = blockIdx.x * 128, n0 = blockIdx.y * 128;
  // staging: chunk e = r*256+tid -> (row = e>>2, ch = e&3); LDS linear at e*16B.
  // source chunk pre-swizzled: cs = ch ^ ((row ^ row>>2)&3)  [involution]
  int row_s = tid >> 2, ch_s = tid & 3;
  int cs = ch_s ^ ((row_s ^ (row_s >> 2)) & 3);
  const u16* Ap = A + (size_t)(m0 + row_s) * K + cs * 8;
  const u16* Bp = Bt + (size_t)(n0 + row_s) * K + cs * 8;
  size_t step64 = (size_t)64 * K;
  int s2a = (li ^ (li >> 2)) & 3;  // = swizzle of every row this lane reads
  f32x4 acc[4][4] = {};
  for (int k0 = 0; k0 < K; k0 += 32) {
    __syncthreads();
    gload16(Ap + k0, &As[w * 512]);
    gload16(Ap + step64 + k0, &As[2048 + w * 512]);
    gload16(Bp + k0, &Bs[w * 512]);
    gload16(Bp + step64 + k0, &Bs[2048 + w * 512]);
    __syncthreads();
    bf16x8 af[4], bfr[4];
#pragma unroll
    for (int i = 0; i < 4; i++) {
      af[i] = *(const bf16x8*)&As[(wr * 64 + i * 16 + li) * 32 + (g ^ s2a) * 8];
      bfr[i] = *(const bf16x8*)&Bs[(wc * 64 + i * 16 + li) * 32 + (g ^ s2a) * 8];
    }
#pragma unroll
    for (int mi = 0; mi < 4; mi++)
#pragma unroll
      for (int ni = 0; ni < 4; ni++)
        acc[mi][ni] = __builtin_amdgcn_mfma_f32_16x16x32_bf16(af[mi], bfr[ni], acc[mi][ni], 0, 0, 0);
  }
#pragma unroll
  for (int mi = 0; mi < 4; mi++)
#pragma unroll
    for (int ni = 0; ni < 4; ni++) {
      int gn = n0 + wc * 64 + ni * 16 + li;
      float bv = bias[gn];
#pragma unroll
      for (int r = 0; r < 4; r++) {
        int gm = m0 + wr * 64 + mi * 16 + g * 4 + r;
        float v = acc[mi][ni][r] + bv;
        if (RES) v += resid[(size_t)gm * Nd + gn];
        if (GELU_) v = 0.5f * v * (1.0f + erff(v * 0.70710678118654752f));
        if (OUTF) outf[(size_t)gm * Nd + gn] = v;
        if (OUTB) outb[(size_t)gm * Nd + gn] = f2b(v);
      }
    }
}

// ---------------- flash attention, swapped-QK^T, swizzled LDS, KVBLK=64 ----
// grid 512 flat: bh = idx&15 (XCD locality), qb-block = idx>>4. 4 waves x 16 q.
template <bool CAUSAL>
__global__ __launch_bounds__(256) void attn_fwd(
    const u16* __restrict__ Q, const u16* __restrict__ Kp,
    const u16* __restrict__ Vp, u16* __restrict__ O, int qs, int kvs) {
  __shared__ u16 Ks[64 * 64];      // [key][d]   swizzled rows
  __shared__ u16 Vt[64 * 64];      // [d][key]   swizzled rows
  __shared__ u16 Ps[4][16 * 64];   // per-wave P [q][key] swizzled rows
  int tid = threadIdx.x;
  int lane = tid & 63, w = tid >> 6;
  int g = lane >> 4, li = lane & 15;
  int idx = blockIdx.x;
  int bh = idx & 15;
  int qbi = idx >> 4;
  if (CAUSAL) qbi = (SEQ / 64 - 1) - qbi;  // heavy blocks first
  int qb = qbi * 64;
  int b = bh >> 3, h = bh & 7;
  const u16* Qh = Q + (size_t)b * SEQ * qs + h * 64;
  const u16* Kh = Kp + (size_t)b * SEQ * kvs + h * 64;
  const u16* Vh = Vp + (size_t)b * SEQ * kvs + h * 64;
  int qrow = qb + w * 16 + li;   // softmax row owned by this lane
  int q_hi = qb + w * 16 + 15;
  bf16x8 qa[2];
#pragma unroll
  for (int ks = 0; ks < 2; ks++)
    qa[ks] = *(const bf16x8*)&Qh[(size_t)qrow * qs + ks * 32 + g * 8];
  f32x4 o[4] = {};
  float mreg = -1e30f, lreg = 0.f;
  int sk_key = tid >> 2, sk_c = (tid & 3) * 2;
  int sv_k2 = (tid >> 3) * 2, sv_dg = (tid & 7) * 8;
  int kv_end = CAUSAL ? qb + 64 : SEQ;
  for (int kv0 = 0; kv0 < kv_end; kv0 += 64) {
    __syncthreads();
    {
      // K stage: row sk_key, chunks sk_c, sk_c+1 (b128 writes, swizzled)
      uint4 ka = *(const uint4*)&Kh[(size_t)(kv0 + sk_key) * kvs + sk_c * 8];
      uint4 kc = *(const uint4*)&Kh[(size_t)(kv0 + sk_key) * kvs + sk_c * 8 + 8];
      int sw = swz64(sk_key);
      *(uint4*)&Ks[sk_key * 64 + ((sk_c ^ sw) * 8)] = ka;
      *(uint4*)&Ks[sk_key * 64 + (((sk_c + 1) ^ sw) * 8)] = kc;
      // V stage transposed: keys sv_k2, sv_k2+1, d-chunk sv_dg (u32 pair writes)
      uint4 v0 = *(const uint4*)&Vh[(size_t)(kv0 + sv_k2) * kvs + sv_dg];
      uint4 v1 = *(const uint4*)&Vh[(size_t)(kv0 + sv_k2 + 1) * kvs + sv_dg];
      const u16* a0 = (const u16*)&v0;
      const u16* a1 = (const u16*)&v1;
#pragma unroll
      for (int jj = 0; jj < 8; jj++) {
        int d = sv_dg + jj;
        unsigned pk = (unsigned)a0[jj] | ((unsigned)a1[jj] << 16);
        *(unsigned*)&Vt[d * 64 + (sv_k2 ^ (swz64(d) << 3))] = pk;
      }
    }
    __syncthreads();
    if (!CAUSAL || kv0 <= q_hi) {
      // S^T = K . Q^T : lane holds S[k = kv0+nt*16+g*4+r][q = li]
      f32x4 S[4] = {};
#pragma unroll
      for (int nt = 0; nt < 4; nt++) {
        int krow = nt * 16 + li;
        int sw = swz64(krow) << 3;
#pragma unroll
        for (int ks = 0; ks < 2; ks++) {
          bf16x8 kb = *(const bf16x8*)&Ks[krow * 64 + ((ks * 32 + g * 8) ^ sw)];
          S[nt] = __builtin_amdgcn_mfma_f32_16x16x32_bf16(kb, qa[ks], S[nt], 0, 0, 0);
        }
      }
      float pm = -1e30f;
#pragma unroll
      for (int nt = 0; nt < 4; nt++)
#pragma unroll
        for (int r = 0; r < 4; r++) {
          float s = S[nt][r] * 0.125f;  // 1/sqrt(64)
          if (CAUSAL && (kv0 + nt * 16 + g * 4 + r > qrow)) s = -1e30f;
          S[nt][r] = s;
          pm = fmaxf(pm, s);
        }
      pm = fmaxf(pm, __shfl_xor(pm, 16, 64));
      pm = fmaxf(pm, __shfl_xor(pm, 32, 64));
      float nm = fmaxf(mreg, pm);
      float csc = __expf(mreg - nm);
      float rs = 0.f;
#pragma unroll
      for (int nt = 0; nt < 4; nt++)
#pragma unroll
        for (int r = 0; r < 4; r++) {
          float e = __expf(S[nt][r] - nm);
          S[nt][r] = e;
          rs += e;
        }
      rs += __shfl_xor(rs, 16, 64);
      rs += __shfl_xor(rs, 32, 64);
      lreg = lreg * csc + rs;
      mreg = nm;
      float cscr[4];
#pragma unroll
      for (int r = 0; r < 4; r++)
        cscr[r] = __shfl(csc, (lane & 48) | (g * 4 + r), 64);
#pragma unroll
      for (int nt = 0; nt < 4; nt++)
#pragma unroll
        for (int r = 0; r < 4; r++) o[nt][r] *= cscr[r];
      // P -> per-wave LDS (q = li rows), then A-fragments
      int swp = swz64(li) << 3;
      u16* pw = Ps[w];
#pragma unroll
      for (int nt = 0; nt < 4; nt++)
#pragma unroll
        for (int rp = 0; rp < 2; rp++) {
          unsigned pk = (unsigned)f2b(S[nt][2 * rp]) |
                        ((unsigned)f2b(S[nt][2 * rp + 1]) << 16);
          *(unsigned*)&pw[li * 64 + ((nt * 16 + g * 4 + 2 * rp) ^ swp)] = pk;
        }
      bf16x8 pa[2];
#pragma unroll
      for (int k2 = 0; k2 < 2; k2++)
        pa[k2] = *(const bf16x8*)&pw[li * 64 + ((k2 * 32 + g * 8) ^ swp)];
#pragma unroll
      for (int nd = 0; nd < 4; nd++) {
        int drow = nd * 16 + li;
        int swv = swz64(drow) << 3;
#pragma unroll
        for (int k2 = 0; k2 < 2; k2++) {
          bf16x8 vb = *(const bf16x8*)&Vt[drow * 64 + ((k2 * 32 + g * 8) ^ swv)];
          o[nd] = __builtin_amdgcn_mfma_f32_16x16x32_bf16(pa[k2], vb, o[nd], 0, 0, 0);
        }
      }
    }
  }
  float linv = 1.0f / lreg;
  float invr[4];
#pragma unroll
  for (int r = 0; r < 4; r++)
    invr[r] = __shfl(linv, (lane & 48) | (g * 4 + r), 64);
#pragma unroll
  for (int nd = 0; nd < 4; nd++)
#pragma unroll
    for (int r = 0; r < 4; r++)
      O[(size_t)b * SEQ * EMB + (size_t)(qb + w * 16 + g * 4 + r) * EMB + h * 64 + nd * 16 + li] =
          f2b(o[nd][r] * invr[r]);
}

// ---------------- LayerNorm (one wave per 512-row), fp32 + optional bf16 out ----
__global__ __launch_bounds__(256) void ln_fused(
    const float* __restrict__ in, const float* __restrict__ gamma,
    const float* __restrict__ beta, float* __restrict__ outf, u16* __restrict__ outb) {
  int row = blockIdx.x * 4 + (threadIdx.x >> 6);
  int lane = threadIdx.x & 63;
  const float* p = in + (size_t)row * EMB + lane * 8;
  float v[8];
  *(float4*)&v[0] = *(const float4*)p;
  *(float4*)&v[4] = *(const float4*)(p + 4);
  float s = 0.f, q = 0.f;
#pragma unroll
  for (int j = 0; j < 8; j++) { s += v[j]; q += v[j] * v[j]; }
#pragma unroll
  for (int d = 1; d < 64; d <<= 1) {
    s += __shfl_xor(s, d, 64);
    q += __shfl_xor(q, d, 64);
  }
  float mu = s * (1.0f / EMB);
  float var = q * (1.0f / EMB) - mu * mu;
  float rsig = rsqrtf(var + 1e-5f);
  float gg[8], bb[8];
  *(float4*)&gg[0] = *(const float4*)(gamma + lane * 8);
  *(float4*)&gg[4] = *(const float4*)(gamma + lane * 8 + 4);
  *(float4*)&bb[0] = *(const float4*)(beta + lane * 8);
  *(float4*)&bb[4] = *(const float4*)(beta + lane * 8 + 4);
  float o[8];
#pragma unroll
  for (int j = 0; j < 8; j++) o[j] = (v[j] - mu) * rsig * gg[j] + bb[j];
  float* po = outf + (size_t)row * EMB + lane * 8;
  *(float4*)po = *(float4*)&o[0];
  *(float4*)(po + 4) = *(float4*)&o[4];
  if (outb) {
    uint4 u;
    u.x = f2b(o[0]) | ((unsigned)f2b(o[1]) << 16);
    u.y = f2b(o[2]) | ((unsigned)f2b(o[3]) << 16);
    u.z = f2b(o[4]) | ((unsigned)f2b(o[5]) << 16);
    u.w = f2b(o[6]) | ((unsigned)f2b(o[7]) << 16);
    *(uint4*)(outb + (size_t)row * EMB + lane * 8) = u;
  }
}

extern "C" void kernel_launch(void* const* d_in, const int* in_sizes, int n_in,
                              void* d_out, int out_size, void* d_ws, size_t ws_size,
                              hipStream_t stream) {
  const float* x     = (const float*)d_in[0];
  const float* enc   = (const float*)d_in[1];
  const float* sa_wq = (const float*)d_in[2];
  const float* sa_bq = (const float*)d_in[3];
  const float* sa_wk = (const float*)d_in[4];
  const float* sa_bk = (const float*)d_in[5];
  const float* sa_wv = (const float*)d_in[6];
  const float* sa_bv = (const float*)d_in[7];
  const float* sa_wo = (const float*)d_in[8];
  const float* sa_bo = (const float*)d_in[9];
  const float* ca_wq = (const float*)d_in[10];
  const float* ca_bq = (const float*)d_in[11];
  const float* ca_wk = (const float*)d_in[12];
  const float* ca_bk = (const float*)d_in[13];
  const float* ca_wv = (const float*)d_in[14];
  const float* ca_bv = (const float*)d_in[15];
  const float* ca_wo = (const float*)d_in[16];
  const float* ca_bo = (const float*)d_in[17];
  const float* ln1_g = (const float*)d_in[18];
  const float* ln1_b = (const float*)d_in[19];
  const float* ln2_g = (const float*)d_in[20];
  const float* ln2_b = (const float*)d_in[21];
  const float* ln3_g = (const float*)d_in[22];
  const float* ln3_b = (const float*)d_in[23];
  const float* ff_w1 = (const float*)d_in[24];
  const float* ff_b1 = (const float*)d_in[25];
  const float* ff_w2 = (const float*)d_in[26];
  const float* ff_b2 = (const float*)d_in[27];

  char* ws = (char*)d_ws;
  size_t off = 0;
  auto alloc = [&](size_t bytes) {
    void* p = ws + off;
    off = (off + bytes + 255) & ~(size_t)255;
    return p;
  };
  u16* qkvT_sa  = (u16*)alloc((size_t)1536 * EMB * 2);
  u16* oT_sa    = (u16*)alloc((size_t)EMB * EMB * 2);
  u16* qT_ca    = (u16*)alloc((size_t)EMB * EMB * 2);
  u16* kvT_ca   = (u16*)alloc((size_t)1024 * EMB * 2);
  u16* oT_ca    = (u16*)alloc((size_t)EMB * EMB * 2);
  u16* w1T      = (u16*)alloc((size_t)FF * EMB * 2);
  u16* w2T      = (u16*)alloc((size_t)EMB * FF * 2);
  float* bqkv_sa = (float*)alloc(1536 * 4);
  float* bkv_ca  = (float*)alloc(1024 * 4);
  u16* xb    = (u16*)alloc((size_t)MTOT * EMB * 2);
  u16* encb  = (u16*)alloc((size_t)MTOT * EMB * 2);
  u16* qkv   = (u16*)alloc((size_t)MTOT * 1536 * 2);
  u16* attnb = (u16*)alloc((size_t)MTOT * EMB * 2);
  float* t0  = (float*)alloc((size_t)MTOT * EMB * 4);
  float* x1  = (float*)alloc((size_t)MTOT * EMB * 4);
  u16* x1b   = (u16*)alloc((size_t)MTOT * EMB * 2);
  float* x2  = (float*)alloc((size_t)MTOT * EMB * 4);
  u16* x2b   = (u16*)alloc((size_t)MTOT * EMB * 2);
  u16* hbuf  = (u16*)alloc((size_t)MTOT * FF * 2);
  u16* qca  = xb;   // xb dead after SA-QKV gemm
  u16* kvca = qkv;  // qkv dead after SA attention

  prep_all<<<dim3(64, 16, 12), 256, 0, stream>>>(
      sa_wq, sa_wk, sa_wv, sa_wo, ca_wq, ca_wk, ca_wv, ca_wo, ff_w1, ff_w2,
      qkvT_sa, qkvT_sa + 512 * EMB, qkvT_sa + 1024 * EMB, oT_sa, qT_ca,
      kvT_ca, kvT_ca + 512 * EMB, oT_ca, w1T, w2T,
      x, xb, enc, encb,
      sa_bq, sa_bk, sa_bv, bqkv_sa, ca_bk, ca_bv, bkv_ca);

  // ---- self-attention block ----
  gemm_bt<true, false, false, false><<<dim3(32, 12), 256, 0, stream>>>(
      xb, qkvT_sa, bqkv_sa, nullptr, qkv, nullptr, EMB, 1536);
  attn_fwd<true><<<512, 256, 0, stream>>>(qkv, qkv + 512, qkv + 1024, attnb, 1536, 1536);
  gemm_bt<false, true, true, false><<<dim3(32, 4), 256, 0, stream>>>(
      attnb, oT_sa, sa_bo, x, nullptr, t0, EMB, EMB);
  ln_fused<<<1024, 256, 0, stream>>>(t0, ln1_g, ln1_b, x1, x1b);

  // ---- cross-attention block ----
  gemm_bt<true, false, false, false><<<dim3(32, 4), 256, 0, stream>>>(
      x1b, qT_ca, ca_bq, nullptr, qca, nullptr, EMB, EMB);
  gemm_bt<true, false, false, false><<<dim3(32, 8), 256, 0, stream>>>(
      encb, kvT_ca, bkv_ca, nullptr, kvca, nullptr, EMB, 1024);
  attn_fwd<false><<<512, 256, 0, stream>>>(qca, kvca, kvca + 512, attnb, EMB, 1024);
  gemm_bt<false, true, true, false><<<dim3(32, 4), 256, 0, stream>>>(
      attnb, oT_ca, ca_bo, x1, nullptr, t0, EMB, EMB);
  ln_fused<<<1024, 256, 0, stream>>>(t0, ln2_g, ln2_b, x2, x2b);

  // ---- FFN block ----
  gemm_bt<true, false, false, true><<<dim3(32, 16), 256, 0, stream>>>(
      x2b, w1T, ff_b1, nullptr, hbuf, nullptr, EMB, FF);
  gemm_bt<false, true, true, false><<<dim3(32, 4), 256, 0, stream>>>(
      hbuf, w2T, ff_b2, x2, nullptr, t0, FF, EMB);
  ln_fused<<<1024, 256, 0, stream>>>(t0, ln3_g, ln3_b, (float*)d_out, nullptr);
}

// Round 3
// 355.651 us; speedup vs baseline: 1.5188x; 1.0668x over previous
//
#include <hip/hip_runtime.h>
#include <hip/hip_bf16.h>

typedef __bf16 bf16x8 __attribute__((ext_vector_type(8)));
typedef float f32x4 __attribute__((ext_vector_type(4)));
typedef unsigned short u16;

#define EMB 512
#define FF 2048
#define MTOT 4096
#define SEQ 2048

__device__ __forceinline__ u16 f2b(float f) {
  return __builtin_bit_cast(u16, (__bf16)f);
}

__device__ __forceinline__ void gload16(const u16* g, u16* l) {
  __builtin_amdgcn_global_load_lds(
      (const __attribute__((address_space(1))) unsigned int*)g,
      (__attribute__((address_space(3))) unsigned int*)l, 16, 0, 0);
}

// ---------------- fused prep: 10 weight transposes + 2 cvt + 2 bias concats ----
__global__ __launch_bounds__(256) void prep_all(
    const float* s0, const float* s1, const float* s2, const float* s3,
    const float* s4, const float* s5, const float* s6, const float* s7,
    const float* s8, const float* s9,
    u16* d0, u16* d1, u16* d2, u16* d3, u16* d4,
    u16* d5, u16* d6, u16* d7, u16* d8, u16* d9,
    const float* x, u16* xb, const float* enc, u16* encb,
    const float* bq1, const float* bk1, const float* bv1, float* bqkv,
    const float* bk2, const float* bv2, float* bkv) {
  int z = blockIdx.z, bx = blockIdx.x, by = blockIdx.y;
  int tid = threadIdx.x;
  if (z >= 10) {  // fp32 -> bf16 cvt of x / enc
    int fb = by * 64 + bx;
    const float* src = (z == 10) ? x : enc;
    u16* dst = (z == 10) ? xb : encb;
    size_t base = (size_t)fb * 2048 + tid * 8;
    float4 a = *(const float4*)(src + base);
    float4 b = *(const float4*)(src + base + 4);
    uint4 u;
    u.x = f2b(a.x) | ((unsigned)f2b(a.y) << 16);
    u.y = f2b(a.z) | ((unsigned)f2b(a.w) << 16);
    u.z = f2b(b.x) | ((unsigned)f2b(b.y) << 16);
    u.w = f2b(b.z) | ((unsigned)f2b(b.w) << 16);
    *(uint4*)(dst + base) = u;
    return;
  }
  if (z == 0 && bx == 16 && by == 0) {
    for (int i = tid; i < 1536; i += 256)
      bqkv[i] = (i < 512) ? bq1[i] : (i < 1024 ? bk1[i - 512] : bv1[i - 1024]);
    return;
  }
  if (z == 1 && bx == 16 && by == 0) {
    for (int i = tid; i < 1024; i += 256)
      bkv[i] = (i < 512) ? bk2[i] : bv2[i - 512];
    return;
  }
  const float* src; u16* dst; int K, N;
  switch (z) {
    case 0: src = s0; dst = d0; K = 512; N = 512; break;
    case 1: src = s1; dst = d1; K = 512; N = 512; break;
    case 2: src = s2; dst = d2; K = 512; N = 512; break;
    case 3: src = s3; dst = d3; K = 512; N = 512; break;
    case 4: src = s4; dst = d4; K = 512; N = 512; break;
    case 5: src = s5; dst = d5; K = 512; N = 512; break;
    case 6: src = s6; dst = d6; K = 512; N = 512; break;
    case 7: src = s7; dst = d7; K = 512; N = 512; break;
    case 8: src = s8; dst = d8; K = 512; N = 2048; break;
    default: src = s9; dst = d9; K = 2048; N = 512; break;
  }
  int ntl, ktl;
  if (z == 9) { ktl = bx; ntl = by; } else { ntl = bx; ktl = by; }
  if (ntl * 32 >= N || ktl * 32 >= K) return;
  __shared__ float t[32][33];
  int tx = tid & 31, ty = tid >> 5;
  int n0 = ntl * 32, k0 = ktl * 32;
#pragma unroll
  for (int i = 0; i < 4; i++)
    t[ty + i * 8][tx] = src[(size_t)(k0 + ty + i * 8) * N + n0 + tx];
  __syncthreads();
#pragma unroll
  for (int i = 0; i < 4; i++)
    dst[(size_t)(n0 + ty + i * 8) * K + k0 + tx] = f2b(t[tx][ty + i * 8]);
}

// ---------------- bf16 GEMM: dbuf LDS, 1 barrier/iter, global_load_lds ----
// C[M,Nd] = A[M,K] @ Bt[Nd,K]^T + bias (+res,+gelu). BMx128 tile, 4 waves, BK=32.
template <int BM, bool OUTB, bool OUTF, bool RES, bool GELU_>
__global__ __launch_bounds__(256) void gemm_bt(
    const u16* __restrict__ A, const u16* __restrict__ Bt,
    const float* __restrict__ bias, const float* __restrict__ resid,
    u16* __restrict__ outb, float* __restrict__ outf, int K, int Nd) {
  constexpr int MI = BM / 32;  // acc M-fragments per wave
  __shared__ u16 As[2][BM * 32];
  __shared__ u16 Bs[2][128 * 32];
  int tid = threadIdx.x;
  int lane = tid & 63, w = tid >> 6;
  int g = lane >> 4, li = lane & 15;
  int wr = w >> 1, wc = w & 1;
  int m0 = blockIdx.x * BM, n0 = blockIdx.y * 128;
  // staging map (lane-linear LDS dest, pre-swizzled global source chunk)
  int row_s = tid >> 2, ch_s = tid & 3;
  int cs = ch_s ^ ((row_s ^ (row_s >> 2)) & 3);  // involution; +64-row invariant
  const u16* Ap = A + (size_t)(m0 + row_s) * K + cs * 8;
  const u16* Bp = Bt + (size_t)(n0 + row_s) * K + cs * 8;
  size_t step64 = (size_t)64 * K;
  int s2a = (li ^ (li >> 2)) & 3;  // swizzle of every row this lane reads
  f32x4 acc[MI][4] = {};
  int T = K >> 5;
  auto stage = [&](int t, int buf) {
    int k0 = t << 5;
    u16* Ad = &As[buf][w * 512];
    u16* Bd = &Bs[buf][w * 512];
    gload16(Ap + k0, Ad);
    if constexpr (BM == 128) gload16(Ap + step64 + k0, Ad + 2048);
    gload16(Bp + k0, Bd);
    gload16(Bp + step64 + k0, Bd + 2048);
  };
  stage(0, 0);
  __syncthreads();
  for (int t = 0; t < T; t++) {
    int cur = t & 1;
    if (t + 1 < T) stage(t + 1, cur ^ 1);
    bf16x8 af[MI], bfr[4];
#pragma unroll
    for (int i = 0; i < MI; i++)
      af[i] = *(const bf16x8*)&As[cur][(wr * (BM / 2) + i * 16 + li) * 32 + (g ^ s2a) * 8];
#pragma unroll
    for (int i = 0; i < 4; i++)
      bfr[i] = *(const bf16x8*)&Bs[cur][(wc * 64 + i * 16 + li) * 32 + (g ^ s2a) * 8];
#pragma unroll
    for (int mi = 0; mi < MI; mi++)
#pragma unroll
      for (int ni = 0; ni < 4; ni++)
        acc[mi][ni] = __builtin_amdgcn_mfma_f32_16x16x32_bf16(af[mi], bfr[ni], acc[mi][ni], 0, 0, 0);
    __syncthreads();
  }
#pragma unroll
  for (int mi = 0; mi < MI; mi++)
#pragma unroll
    for (int ni = 0; ni < 4; ni++) {
      int gn = n0 + wc * 64 + ni * 16 + li;
      float bv = bias[gn];
#pragma unroll
      for (int r = 0; r < 4; r++) {
        int gm = m0 + wr * (BM / 2) + mi * 16 + g * 4 + r;
        float v = acc[mi][ni][r] + bv;
        if (RES) v += resid[(size_t)gm * Nd + gn];
        if (GELU_) v = 0.5f * v * (1.0f + erff(v * 0.70710678118654752f));
        if (OUTF) outf[(size_t)gm * Nd + gn] = v;
        if (OUTB) outb[(size_t)gm * Nd + gn] = f2b(v);
      }
    }
}

// ---------------- flash attention: KVBLK=128, dbuf, 1 barrier/iter ----
// grid 512 flat: bh = idx&15, qb-block(64) = idx>>4. 4 waves x 16 q.
template <bool CAUSAL>
__global__ __launch_bounds__(256) void attn_fwd(
    const u16* __restrict__ Q, const u16* __restrict__ Kp,
    const u16* __restrict__ Vp, u16* __restrict__ O, int qs, int kvs) {
  __shared__ u16 Ks[2][128 * 64];   // [key][d] rows 64, chunk-swizzled
  __shared__ u16 Vt[2][64 * 128];   // [d][key] rows 128, chunk-swizzled
  __shared__ u16 Ps[4][16 * 128];   // per-wave P [q][key]
  int tid = threadIdx.x;
  int lane = tid & 63, w = tid >> 6;
  int g = lane >> 4, li = lane & 15;
  int idx = blockIdx.x;
  int bh = idx & 15;
  int qbi = idx >> 4;
  if (CAUSAL) qbi = (SEQ / 64 - 1) - qbi;  // heavy first
  int qb = qbi * 64;
  int b = bh >> 3, h = bh & 7;
  const u16* Qh = Q + (size_t)b * SEQ * qs + h * 64;
  const u16* Kh = Kp + (size_t)b * SEQ * kvs + h * 64;
  const u16* Vh = Vp + (size_t)b * SEQ * kvs + h * 64;
  int qrow = qb + w * 16 + li;
  // Q fragment, pre-scaled by 1/sqrt(64) (exact in bf16)
  bf16x8 qa[2];
#pragma unroll
  for (int ks = 0; ks < 2; ks++) {
    bf16x8 tq = *(const bf16x8*)&Qh[(size_t)qrow * qs + ks * 32 + g * 8];
#pragma unroll
    for (int j = 0; j < 8; j++) tq[j] = (__bf16)((float)tq[j] * 0.125f);
    qa[ks] = tq;
  }
  // K staging via global_load_lds: 4 gloads/thread, lane-linear dest
  int kcc = lane & 7;
  const u16* Ksrc[4];
#pragma unroll
  for (int j = 0; j < 4; j++) {
    int row = j * 32 + w * 8 + (lane >> 3);
    int sw = ((j * 4 + w) ^ (lane >> 3)) & 7;
    Ksrc[j] = Kh + (size_t)row * kvs + (kcc ^ sw) * 8;
  }
  size_t kstep = (size_t)128 * kvs;
  // V staging: thread owns keys 4*kq..+3, d-chunk dcv
  int kq = tid & 31, dcv = tid >> 5;
  const u16* Vsrc = Vh + (size_t)(4 * kq) * kvs + dcv * 8;
  uint4 vr[4];
  auto stageK = [&](int t, int buf) {
    size_t o = (size_t)t * kstep;
    u16* dst = &Ks[buf][w * 512];
#pragma unroll
    for (int j = 0; j < 4; j++) gload16(Ksrc[j] + o, dst + j * 2048);
  };
  auto loadV = [&](int t) {
    size_t o = (size_t)t * kstep;
#pragma unroll
    for (int kk = 0; kk < 4; kk++)
      vr[kk] = *(const uint4*)(Vsrc + o + (size_t)kk * kvs);
  };
  auto writeV = [&](int buf) {
    const u16* a0 = (const u16*)&vr[0];
    const u16* a1 = (const u16*)&vr[1];
    const u16* a2 = (const u16*)&vr[2];
    const u16* a3 = (const u16*)&vr[3];
#pragma unroll
    for (int jj = 0; jj < 8; jj++) {
      int d = dcv * 8 + jj;
      int swv = ((d >> 3) ^ d) & 15;
      uint2 pk;
      pk.x = (unsigned)a0[jj] | ((unsigned)a1[jj] << 16);
      pk.y = (unsigned)a2[jj] | ((unsigned)a3[jj] << 16);
      *(uint2*)&Vt[buf][d * 128 + ((kq >> 1) ^ swv) * 8 + 4 * (kq & 1)] = pk;
    }
  };
  int T = CAUSAL ? (qb >> 7) + 1 : SEQ / 128;
  stageK(0, 0);
  loadV(0);
  writeV(0);
  __syncthreads();
  f32x4 o[4] = {};
  float mreg = -1e30f, lreg = 0.f;
  for (int t = 0; t < T; t++) {
    int cur = t & 1;
    if (t + 1 < T) { stageK(t + 1, cur ^ 1); loadV(t + 1); }
    int kv0 = t << 7;
    // S^T = K.Q^T : lane holds S[k = kv0+nt*16+g*4+r][q = li]
    f32x4 S[8] = {};
    __builtin_amdgcn_s_setprio(1);
#pragma unroll
    for (int nt = 0; nt < 8; nt++) {
      int krow = nt * 16 + li;
      int sw = ((krow >> 3) ^ krow) & 7;
#pragma unroll
      for (int ks = 0; ks < 2; ks++) {
        bf16x8 kb = *(const bf16x8*)&Ks[cur][krow * 64 + ((ks * 4 + g) ^ sw) * 8];
        S[nt] = __builtin_amdgcn_mfma_f32_16x16x32_bf16(kb, qa[ks], S[nt], 0, 0, 0);
      }
    }
    __builtin_amdgcn_s_setprio(0);
    float pm = -1e30f;
#pragma unroll
    for (int nt = 0; nt < 8; nt++)
#pragma unroll
      for (int r = 0; r < 4; r++) {
        float s = S[nt][r];
        if (CAUSAL && (kv0 + nt * 16 + g * 4 + r > qrow)) s = -1e30f;
        S[nt][r] = s;
        pm = fmaxf(pm, s);
      }
    pm = fmaxf(pm, __shfl_xor(pm, 16, 64));
    pm = fmaxf(pm, __shfl_xor(pm, 32, 64));
    float nm = fmaxf(mreg, pm);
    float csc = __expf(mreg - nm);
    float rs = 0.f;
#pragma unroll
    for (int nt = 0; nt < 8; nt++)
#pragma unroll
      for (int r = 0; r < 4; r++) {
        float e = __expf(S[nt][r] - nm);
        S[nt][r] = e;
        rs += e;
      }
    rs += __shfl_xor(rs, 16, 64);
    rs += __shfl_xor(rs, 32, 64);
    lreg = lreg * csc + rs;
    mreg = nm;
    // P -> per-wave LDS as b64 (bank-balanced)
#pragma unroll
    for (int nt = 0; nt < 8; nt++) {
      int cp = 2 * nt + (g >> 1);
      uint2 pk;
      pk.x = (unsigned)f2b(S[nt][0]) | ((unsigned)f2b(S[nt][1]) << 16);
      pk.y = (unsigned)f2b(S[nt][2]) | ((unsigned)f2b(S[nt][3]) << 16);
      *(uint2*)&Ps[w][li * 128 + ((cp ^ li) * 8) + 4 * (g & 1)] = pk;
    }
    float cscr[4];
#pragma unroll
    for (int r = 0; r < 4; r++)
      cscr[r] = __shfl(csc, (lane & 48) | (g * 4 + r), 64);
#pragma unroll
    for (int nd = 0; nd < 4; nd++)
#pragma unroll
      for (int r = 0; r < 4; r++) o[nd][r] *= cscr[r];
    bf16x8 pa[4];
#pragma unroll
    for (int k2 = 0; k2 < 4; k2++)
      pa[k2] = *(const bf16x8*)&Ps[w][li * 128 + (((k2 * 4 + g) ^ li) * 8)];
    __builtin_amdgcn_s_setprio(1);
#pragma unroll
    for (int nd = 0; nd < 4; nd++) {
      int d = nd * 16 + li;
      int swv = ((d >> 3) ^ d) & 15;
#pragma unroll
      for (int k2 = 0; k2 < 4; k2++) {
        bf16x8 vb = *(const bf16x8*)&Vt[cur][d * 128 + (((k2 * 4 + g) ^ swv) * 8)];
        o[nd] = __builtin_amdgcn_mfma_f32_16x16x32_bf16(pa[k2], vb, o[nd], 0, 0, 0);
      }
    }
    __builtin_amdgcn_s_setprio(0);
    if (t + 1 < T) writeV(cur ^ 1);
    __syncthreads();
  }
  float linv = 1.0f / lreg;
  float invr[4];
#pragma unroll
  for (int r = 0; r < 4; r++)
    invr[r] = __shfl(linv, (lane & 48) | (g * 4 + r), 64);
#pragma unroll
  for (int nd = 0; nd < 4; nd++)
#pragma unroll
    for (int r = 0; r < 4; r++)
      O[(size_t)b * SEQ * EMB + (size_t)(qb + w * 16 + g * 4 + r) * EMB + h * 64 + nd * 16 + li] =
          f2b(o[nd][r] * invr[r]);
}

// ---------------- LayerNorm (one wave per 512-row), fp32 + optional bf16 out ----
__global__ __launch_bounds__(256) void ln_fused(
    const float* __restrict__ in, const float* __restrict__ gamma,
    const float* __restrict__ beta, float* __restrict__ outf, u16* __restrict__ outb) {
  int row = blockIdx.x * 4 + (threadIdx.x >> 6);
  int lane = threadIdx.x & 63;
  const float* p = in + (size_t)row * EMB + lane * 8;
  float v[8];
  *(float4*)&v[0] = *(const float4*)p;
  *(float4*)&v[4] = *(const float4*)(p + 4);
  float s = 0.f, q = 0.f;
#pragma unroll
  for (int j = 0; j < 8; j++) { s += v[j]; q += v[j] * v[j]; }
#pragma unroll
  for (int d = 1; d < 64; d <<= 1) {
    s += __shfl_xor(s, d, 64);
    q += __shfl_xor(q, d, 64);
  }
  float mu = s * (1.0f / EMB);
  float var = q * (1.0f / EMB) - mu * mu;
  float rsig = rsqrtf(var + 1e-5f);
  float gg[8], bb[8];
  *(float4*)&gg[0] = *(const float4*)(gamma + lane * 8);
  *(float4*)&gg[4] = *(const float4*)(gamma + lane * 8 + 4);
  *(float4*)&bb[0] = *(const float4*)(beta + lane * 8);
  *(float4*)&bb[4] = *(const float4*)(beta + lane * 8 + 4);
  float o[8];
#pragma unroll
  for (int j = 0; j < 8; j++) o[j] = (v[j] - mu) * rsig * gg[j] + bb[j];
  float* po = outf + (size_t)row * EMB + lane * 8;
  *(float4*)po = *(float4*)&o[0];
  *(float4*)(po + 4) = *(float4*)&o[4];
  if (outb) {
    uint4 u;
    u.x = f2b(o[0]) | ((unsigned)f2b(o[1]) << 16);
    u.y = f2b(o[2]) | ((unsigned)f2b(o[3]) << 16);
    u.z = f2b(o[4]) | ((unsigned)f2b(o[5]) << 16);
    u.w = f2b(o[6]) | ((unsigned)f2b(o[7]) << 16);
    *(uint4*)(outb + (size_t)row * EMB + lane * 8) = u;
  }
}

extern "C" void kernel_launch(void* const* d_in, const int* in_sizes, int n_in,
                              void* d_out, int out_size, void* d_ws, size_t ws_size,
                              hipStream_t stream) {
  const float* x     = (const float*)d_in[0];
  const float* enc   = (const float*)d_in[1];
  const float* sa_wq = (const float*)d_in[2];
  const float* sa_bq = (const float*)d_in[3];
  const float* sa_wk = (const float*)d_in[4];
  const float* sa_bk = (const float*)d_in[5];
  const float* sa_wv = (const float*)d_in[6];
  const float* sa_bv = (const float*)d_in[7];
  const float* sa_wo = (const float*)d_in[8];
  const float* sa_bo = (const float*)d_in[9];
  const float* ca_wq = (const float*)d_in[10];
  const float* ca_bq = (const float*)d_in[11];
  const float* ca_wk = (const float*)d_in[12];
  const float* ca_bk = (const float*)d_in[13];
  const float* ca_wv = (const float*)d_in[14];
  const float* ca_bv = (const float*)d_in[15];
  const float* ca_wo = (const float*)d_in[16];
  const float* ca_bo = (const float*)d_in[17];
  const float* ln1_g = (const float*)d_in[18];
  const float* ln1_b = (const float*)d_in[19];
  const float* ln2_g = (const float*)d_in[20];
  const float* ln2_b = (const float*)d_in[21];
  const float* ln3_g = (const float*)d_in[22];
  const float* ln3_b = (const float*)d_in[23];
  const float* ff_w1 = (const float*)d_in[24];
  const float* ff_b1 = (const float*)d_in[25];
  const float* ff_w2 = (const float*)d_in[26];
  const float* ff_b2 = (const float*)d_in[27];

  char* ws = (char*)d_ws;
  size_t off = 0;
  auto alloc = [&](size_t bytes) {
    void* p = ws + off;
    off = (off + bytes + 255) & ~(size_t)255;
    return p;
  };
  u16* qkvT_sa  = (u16*)alloc((size_t)1536 * EMB * 2);
  u16* oT_sa    = (u16*)alloc((size_t)EMB * EMB * 2);
  u16* qT_ca    = (u16*)alloc((size_t)EMB * EMB * 2);
  u16* kvT_ca   = (u16*)alloc((size_t)1024 * EMB * 2);
  u16* oT_ca    = (u16*)alloc((size_t)EMB * EMB * 2);
  u16* w1T      = (u16*)alloc((size_t)FF * EMB * 2);
  u16* w2T      = (u16*)alloc((size_t)EMB * FF * 2);
  float* bqkv_sa = (float*)alloc(1536 * 4);
  float* bkv_ca  = (float*)alloc(1024 * 4);
  u16* xb    = (u16*)alloc((size_t)MTOT * EMB * 2);
  u16* encb  = (u16*)alloc((size_t)MTOT * EMB * 2);
  u16* qkv   = (u16*)alloc((size_t)MTOT * 1536 * 2);
  u16* attnb = (u16*)alloc((size_t)MTOT * EMB * 2);
  float* t0  = (float*)alloc((size_t)MTOT * EMB * 4);
  float* x1  = (float*)alloc((size_t)MTOT * EMB * 4);
  u16* x1b   = (u16*)alloc((size_t)MTOT * EMB * 2);
  float* x2  = (float*)alloc((size_t)MTOT * EMB * 4);
  u16* x2b   = (u16*)alloc((size_t)MTOT * EMB * 2);
  u16* hbuf  = (u16*)alloc((size_t)MTOT * FF * 2);
  u16* qca  = xb;   // xb dead after SA-QKV gemm
  u16* kvca = qkv;  // qkv dead after SA attention

  prep_all<<<dim3(64, 16, 12), 256, 0, stream>>>(
      sa_wq, sa_wk, sa_wv, sa_wo, ca_wq, ca_wk, ca_wv, ca_wo, ff_w1, ff_w2,
      qkvT_sa, qkvT_sa + 512 * EMB, qkvT_sa + 1024 * EMB, oT_sa, qT_ca,
      kvT_ca, kvT_ca + 512 * EMB, oT_ca, w1T, w2T,
      x, xb, enc, encb,
      sa_bq, sa_bk, sa_bv, bqkv_sa, ca_bk, ca_bv, bkv_ca);

  // ---- self-attention block ----
  gemm_bt<128, true, false, false, false><<<dim3(32, 12), 256, 0, stream>>>(
      xb, qkvT_sa, bqkv_sa, nullptr, qkv, nullptr, EMB, 1536);
  attn_fwd<true><<<512, 256, 0, stream>>>(qkv, qkv + 512, qkv + 1024, attnb, 1536, 1536);
  gemm_bt<64, false, true, true, false><<<dim3(64, 4), 256, 0, stream>>>(
      attnb, oT_sa, sa_bo, x, nullptr, t0, EMB, EMB);
  ln_fused<<<1024, 256, 0, stream>>>(t0, ln1_g, ln1_b, x1, x1b);

  // ---- cross-attention block ----
  gemm_bt<64, true, false, false, false><<<dim3(64, 4), 256, 0, stream>>>(
      x1b, qT_ca, ca_bq, nullptr, qca, nullptr, EMB, EMB);
  gemm_bt<128, true, false, false, false><<<dim3(32, 8), 256, 0, stream>>>(
      encb, kvT_ca, bkv_ca, nullptr, kvca, nullptr, EMB, 1024);
  attn_fwd<false><<<512, 256, 0, stream>>>(qca, kvca, kvca + 512, attnb, EMB, 1024);
  gemm_bt<64, false, true, true, false><<<dim3(64, 4), 256, 0, stream>>>(
      attnb, oT_ca, ca_bo, x1, nullptr, t0, EMB, EMB);
  ln_fused<<<1024, 256, 0, stream>>>(t0, ln2_g, ln2_b, x2, x2b);

  // ---- FFN block ----
  gemm_bt<128, true, false, false, true><<<dim3(32, 16), 256, 0, stream>>>(
      x2b, w1T, ff_b1, nullptr, hbuf, nullptr, EMB, FF);
  gemm_bt<64, false, true, true, false><<<dim3(64, 4), 256, 0, stream>>>(
      hbuf, w2T, ff_b2, x2, nullptr, t0, FF, EMB);
  ln_fused<<<1024, 256, 0, stream>>>(t0, ln3_g, ln3_b, (float*)d_out, nullptr);
}

// Round 4
// 339.660 us; speedup vs baseline: 1.5903x; 1.0471x over previous
//
#include <hip/hip_runtime.h>
#include <hip/hip_bf16.h>

typedef __bf16 bf16x8 __attribute__((ext_vector_type(8)));
typedef float f32x4 __attribute__((ext_vector_type(4)));
typedef unsigned short u16;

#define EMB 512
#define FF 2048
#define MTOT 4096
#define SEQ 2048

__device__ __forceinline__ u16 f2b(float f) {
  return __builtin_bit_cast(u16, (__bf16)f);
}

__device__ __forceinline__ void gload16(const u16* g, u16* l) {
  __builtin_amdgcn_global_load_lds(
      (const __attribute__((address_space(1))) unsigned int*)g,
      (__attribute__((address_space(3))) unsigned int*)l, 16, 0, 0);
}

// ---------------- fused prep: 10 weight transposes + 2 cvt + 2 bias concats ----
__global__ __launch_bounds__(256) void prep_all(
    const float* s0, const float* s1, const float* s2, const float* s3,
    const float* s4, const float* s5, const float* s6, const float* s7,
    const float* s8, const float* s9,
    u16* d0, u16* d1, u16* d2, u16* d3, u16* d4,
    u16* d5, u16* d6, u16* d7, u16* d8, u16* d9,
    const float* x, u16* xb, const float* enc, u16* encb,
    const float* bq1, const float* bk1, const float* bv1, float* bqkv,
    const float* bk2, const float* bv2, float* bkv) {
  int z = blockIdx.z, bx = blockIdx.x, by = blockIdx.y;
  int tid = threadIdx.x;
  if (z >= 10) {  // fp32 -> bf16 cvt of x / enc
    int fb = by * 64 + bx;
    const float* src = (z == 10) ? x : enc;
    u16* dst = (z == 10) ? xb : encb;
    size_t base = (size_t)fb * 2048 + tid * 8;
    float4 a = *(const float4*)(src + base);
    float4 b = *(const float4*)(src + base + 4);
    uint4 u;
    u.x = f2b(a.x) | ((unsigned)f2b(a.y) << 16);
    u.y = f2b(a.z) | ((unsigned)f2b(a.w) << 16);
    u.z = f2b(b.x) | ((unsigned)f2b(b.y) << 16);
    u.w = f2b(b.z) | ((unsigned)f2b(b.w) << 16);
    *(uint4*)(dst + base) = u;
    return;
  }
  if (z == 0 && bx == 16 && by == 0) {
    for (int i = tid; i < 1536; i += 256)
      bqkv[i] = (i < 512) ? bq1[i] : (i < 1024 ? bk1[i - 512] : bv1[i - 1024]);
    return;
  }
  if (z == 1 && bx == 16 && by == 0) {
    for (int i = tid; i < 1024; i += 256)
      bkv[i] = (i < 512) ? bk2[i] : bv2[i - 512];
    return;
  }
  const float* src; u16* dst; int K, N;
  switch (z) {
    case 0: src = s0; dst = d0; K = 512; N = 512; break;
    case 1: src = s1; dst = d1; K = 512; N = 512; break;
    case 2: src = s2; dst = d2; K = 512; N = 512; break;
    case 3: src = s3; dst = d3; K = 512; N = 512; break;
    case 4: src = s4; dst = d4; K = 512; N = 512; break;
    case 5: src = s5; dst = d5; K = 512; N = 512; break;
    case 6: src = s6; dst = d6; K = 512; N = 512; break;
    case 7: src = s7; dst = d7; K = 512; N = 512; break;
    case 8: src = s8; dst = d8; K = 512; N = 2048; break;
    default: src = s9; dst = d9; K = 2048; N = 512; break;
  }
  int ntl, ktl;
  if (z == 9) { ktl = bx; ntl = by; } else { ntl = bx; ktl = by; }
  if (ntl * 32 >= N || ktl * 32 >= K) return;
  __shared__ float t[32][33];
  int tx = tid & 31, ty = tid >> 5;
  int n0 = ntl * 32, k0 = ktl * 32;
#pragma unroll
  for (int i = 0; i < 4; i++)
    t[ty + i * 8][tx] = src[(size_t)(k0 + ty + i * 8) * N + n0 + tx];
  __syncthreads();
#pragma unroll
  for (int i = 0; i < 4; i++)
    dst[(size_t)(n0 + ty + i * 8) * K + k0 + tx] = f2b(t[tx][ty + i * 8]);
}

// ---------------- bf16 GEMM: dbuf LDS, 1 barrier/iter, global_load_lds ----
// C[M,Nd] = A[M,K] @ Bt[Nd,K]^T + bias (+res,+gelu). BMxBN tile, 4 waves (2x2).
template <int BM, int BN, bool OUTB, bool OUTF, bool RES, bool GELU_>
__global__ __launch_bounds__(256) void gemm_bt(
    const u16* __restrict__ A, const u16* __restrict__ Bt,
    const float* __restrict__ bias, const float* __restrict__ resid,
    u16* __restrict__ outb, float* __restrict__ outf, int K, int Nd) {
  constexpr int MI = BM / 32;  // per-wave M fragments (wave tile BM/2)
  constexpr int NI = BN / 32;  // per-wave N fragments (wave tile BN/2)
  constexpr int RA = BM / 64;  // staging loads for A per thread
  constexpr int RB = BN / 64;  // staging loads for B per thread
  __shared__ u16 As[2][BM * 32];
  __shared__ u16 Bs[2][BN * 32];
  int tid = threadIdx.x;
  int lane = tid & 63, w = tid >> 6;
  int g = lane >> 4, li = lane & 15;
  int wr = w >> 1, wc = w & 1;
  int m0 = blockIdx.x * BM, n0 = blockIdx.y * BN;
  // staging: chunk c (16B) -> row = c>>2, ch = c&3; LDS linear; source pre-swizzled
  const u16* srcs[RA + RB];
  int ldsoff[RA + RB];
#pragma unroll
  for (int r = 0; r < RA + RB; r++) {
    int ca = (r < RA ? r * 256 : (r - RA) * 256) + tid;
    int row = ca >> 2, chv = ca & 3;
    int csw = chv ^ ((row ^ (row >> 2)) & 3);  // involution
    srcs[r] = (r < RA ? A + (size_t)(m0 + row) * K : Bt + (size_t)(n0 + row) * K) + csw * 8;
    ldsoff[r] = ((r < RA ? r * 256 : (r - RA) * 256) + w * 64) * 8;
  }
  int s2a = (li ^ (li >> 2)) & 3;  // swizzle of every row this lane reads
  f32x4 acc[MI][NI] = {};
  int T = K >> 5;
  auto stage = [&](int t, int buf) {
    int k0 = t << 5;
#pragma unroll
    for (int r = 0; r < RA; r++) gload16(srcs[r] + k0, &As[buf][ldsoff[r]]);
#pragma unroll
    for (int r = RA; r < RA + RB; r++) gload16(srcs[r] + k0, &Bs[buf][ldsoff[r]]);
  };
  stage(0, 0);
  __syncthreads();
  for (int t = 0; t < T; t++) {
    int cur = t & 1;
    if (t + 1 < T) stage(t + 1, cur ^ 1);
    bf16x8 af[MI], bfr[NI];
#pragma unroll
    for (int i = 0; i < MI; i++)
      af[i] = *(const bf16x8*)&As[cur][(wr * (BM / 2) + i * 16 + li) * 32 + (g ^ s2a) * 8];
#pragma unroll
    for (int i = 0; i < NI; i++)
      bfr[i] = *(const bf16x8*)&Bs[cur][(wc * (BN / 2) + i * 16 + li) * 32 + (g ^ s2a) * 8];
#pragma unroll
    for (int mi = 0; mi < MI; mi++)
#pragma unroll
      for (int ni = 0; ni < NI; ni++)
        acc[mi][ni] = __builtin_amdgcn_mfma_f32_16x16x32_bf16(af[mi], bfr[ni], acc[mi][ni], 0, 0, 0);
    __syncthreads();
  }
#pragma unroll
  for (int mi = 0; mi < MI; mi++)
#pragma unroll
    for (int ni = 0; ni < NI; ni++) {
      int gn = n0 + wc * (BN / 2) + ni * 16 + li;
      float bv = bias[gn];
#pragma unroll
      for (int r = 0; r < 4; r++) {
        int gm = m0 + wr * (BM / 2) + mi * 16 + g * 4 + r;
        float v = acc[mi][ni][r] + bv;
        if (RES) v += resid[(size_t)gm * Nd + gn];
        if (GELU_) v = 0.5f * v * (1.0f + erff(v * 0.70710678118654752f));
        if (OUTF) outf[(size_t)gm * Nd + gn] = v;
        if (OUTB) outb[(size_t)gm * Nd + gn] = f2b(v);
      }
    }
}

// ---------------- flash attention: KVBLK=128, dbuf, exp2-domain, defer-max ----
// grid 512 flat: bh = idx&15, qb-block(64) = idx>>4. 4 waves x 16 q.
template <bool CAUSAL>
__global__ __launch_bounds__(256) void attn_fwd(
    const u16* __restrict__ Q, const u16* __restrict__ Kp,
    const u16* __restrict__ Vp, u16* __restrict__ O, int qs, int kvs) {
  __shared__ u16 Ks[2][128 * 64];   // [key][d] rows 64, chunk-swizzled
  __shared__ u16 Vt[2][64 * 128];   // [d][key] rows 128, chunk-swizzled
  __shared__ u16 Ps[4][16 * 128];   // per-wave P [q][key]
  int tid = threadIdx.x;
  int lane = tid & 63, w = tid >> 6;
  int g = lane >> 4, li = lane & 15;
  int idx = blockIdx.x;
  int bh = idx & 15;
  int qbi = idx >> 4;
  if (CAUSAL) qbi = (SEQ / 64 - 1) - qbi;  // heavy first
  int qb = qbi * 64;
  int b = bh >> 3, h = bh & 7;
  const u16* Qh = Q + (size_t)b * SEQ * qs + h * 64;
  const u16* Kh = Kp + (size_t)b * SEQ * kvs + h * 64;
  const u16* Vh = Vp + (size_t)b * SEQ * kvs + h * 64;
  int qrow = qb + w * 16 + li;
  // Q fragment, pre-scaled by log2(e)/sqrt(64) -> softmax in exp2 domain
  bf16x8 qa[2];
#pragma unroll
  for (int ks = 0; ks < 2; ks++) {
    bf16x8 tq = *(const bf16x8*)&Qh[(size_t)qrow * qs + ks * 32 + g * 8];
#pragma unroll
    for (int j = 0; j < 8; j++) tq[j] = (__bf16)((float)tq[j] * 0.18033688011112042f);
    qa[ks] = tq;
  }
  // K staging via global_load_lds: 4 gloads/thread, lane-linear dest
  int kcc = lane & 7;
  const u16* Ksrc[4];
#pragma unroll
  for (int j = 0; j < 4; j++) {
    int row = j * 32 + w * 8 + (lane >> 3);
    int sw = ((j * 4 + w) ^ (lane >> 3)) & 7;
    Ksrc[j] = Kh + (size_t)row * kvs + (kcc ^ sw) * 8;
  }
  size_t kstep = (size_t)128 * kvs;
  // V staging: thread owns keys 4*kq..+3, d-chunk dcv
  int kq = tid & 31, dcv = tid >> 5;
  const u16* Vsrc = Vh + (size_t)(4 * kq) * kvs + dcv * 8;
  uint4 vr[4];
  auto stageK = [&](int t, int buf) {
    size_t o = (size_t)t * kstep;
    u16* dst = &Ks[buf][w * 512];
#pragma unroll
    for (int j = 0; j < 4; j++) gload16(Ksrc[j] + o, dst + j * 2048);
  };
  auto loadV = [&](int t) {
    size_t o = (size_t)t * kstep;
#pragma unroll
    for (int kk = 0; kk < 4; kk++)
      vr[kk] = *(const uint4*)(Vsrc + o + (size_t)kk * kvs);
  };
  auto writeV = [&](int buf) {
    const u16* a0 = (const u16*)&vr[0];
    const u16* a1 = (const u16*)&vr[1];
    const u16* a2 = (const u16*)&vr[2];
    const u16* a3 = (const u16*)&vr[3];
#pragma unroll
    for (int jj = 0; jj < 8; jj++) {
      int d = dcv * 8 + jj;
      int swv = ((d >> 3) ^ d) & 15;
      uint2 pk;
      pk.x = (unsigned)a0[jj] | ((unsigned)a1[jj] << 16);
      pk.y = (unsigned)a2[jj] | ((unsigned)a3[jj] << 16);
      *(uint2*)&Vt[buf][d * 128 + ((kq >> 1) ^ swv) * 8 + 4 * (kq & 1)] = pk;
    }
  };
  int T = CAUSAL ? (qb >> 7) + 1 : SEQ / 128;
  stageK(0, 0);
  loadV(0);
  writeV(0);
  __syncthreads();
  f32x4 o[4] = {};
  float mreg = -1e30f, lreg = 0.f;
  for (int t = 0; t < T; t++) {
    int cur = t & 1;
    if (t + 1 < T) { stageK(t + 1, cur ^ 1); loadV(t + 1); }
    int kv0 = t << 7;
    // S^T = K.Q^T : lane holds S[k = kv0+nt*16+g*4+r][q = li]
    f32x4 S[8] = {};
    __builtin_amdgcn_s_setprio(1);
#pragma unroll
    for (int nt = 0; nt < 8; nt++) {
      int krow = nt * 16 + li;
      int sw = ((krow >> 3) ^ krow) & 7;
#pragma unroll
      for (int ks = 0; ks < 2; ks++) {
        bf16x8 kb = *(const bf16x8*)&Ks[cur][krow * 64 + ((ks * 4 + g) ^ sw) * 8];
        S[nt] = __builtin_amdgcn_mfma_f32_16x16x32_bf16(kb, qa[ks], S[nt], 0, 0, 0);
      }
    }
    __builtin_amdgcn_s_setprio(0);
    if (CAUSAL && (kv0 + 127 > qb + w * 16)) {  // wave-uniform boundary test
#pragma unroll
      for (int nt = 0; nt < 8; nt++) {
        int kb0 = kv0 + nt * 16 + g * 4;
#pragma unroll
        for (int r = 0; r < 4; r++)
          if (kb0 + r > qrow) S[nt][r] = -1e30f;
      }
    }
    f32x4 mx = S[0];
#pragma unroll
    for (int nt = 1; nt < 8; nt++)
#pragma unroll
      for (int r = 0; r < 4; r++) mx[r] = fmaxf(mx[r], S[nt][r]);
    float pm = fmaxf(fmaxf(mx[0], mx[1]), fmaxf(mx[2], mx[3]));
    pm = fmaxf(pm, __shfl_xor(pm, 16, 64));
    pm = fmaxf(pm, __shfl_xor(pm, 32, 64));
    bool need = __any(pm > mreg + 8.0f);  // defer-max: P bounded by 2^8
    float nm = need ? fmaxf(mreg, pm) : mreg;
    f32x4 acc4 = {0.f, 0.f, 0.f, 0.f};
#pragma unroll
    for (int nt = 0; nt < 8; nt++)
#pragma unroll
      for (int r = 0; r < 4; r++) {
        float e = exp2f(S[nt][r] - nm);
        S[nt][r] = e;
        acc4[r] += e;
      }
    float rs = (acc4[0] + acc4[1]) + (acc4[2] + acc4[3]);
    rs += __shfl_xor(rs, 16, 64);
    rs += __shfl_xor(rs, 32, 64);
    if (need) {
      float csc = exp2f(mreg - nm);
      lreg = lreg * csc + rs;
      mreg = nm;
      float cscr[4];
#pragma unroll
      for (int r = 0; r < 4; r++)
        cscr[r] = __shfl(csc, (lane & 48) | (g * 4 + r), 64);
#pragma unroll
      for (int nd = 0; nd < 4; nd++)
#pragma unroll
        for (int r = 0; r < 4; r++) o[nd][r] *= cscr[r];
    } else {
      lreg += rs;
    }
    // P -> per-wave LDS as b64 (bank-balanced)
#pragma unroll
    for (int nt = 0; nt < 8; nt++) {
      int cp = 2 * nt + (g >> 1);
      uint2 pk;
      pk.x = (unsigned)f2b(S[nt][0]) | ((unsigned)f2b(S[nt][1]) << 16);
      pk.y = (unsigned)f2b(S[nt][2]) | ((unsigned)f2b(S[nt][3]) << 16);
      *(uint2*)&Ps[w][li * 128 + ((cp ^ li) * 8) + 4 * (g & 1)] = pk;
    }
    bf16x8 pa[4];
#pragma unroll
    for (int k2 = 0; k2 < 4; k2++)
      pa[k2] = *(const bf16x8*)&Ps[w][li * 128 + (((k2 * 4 + g) ^ li) * 8)];
    __builtin_amdgcn_s_setprio(1);
#pragma unroll
    for (int nd = 0; nd < 4; nd++) {
      int d = nd * 16 + li;
      int swv = ((d >> 3) ^ d) & 15;
#pragma unroll
      for (int k2 = 0; k2 < 4; k2++) {
        bf16x8 vb = *(const bf16x8*)&Vt[cur][d * 128 + (((k2 * 4 + g) ^ swv) * 8)];
        o[nd] = __builtin_amdgcn_mfma_f32_16x16x32_bf16(pa[k2], vb, o[nd], 0, 0, 0);
      }
    }
    __builtin_amdgcn_s_setprio(0);
    if (t + 1 < T) writeV(cur ^ 1);
    __syncthreads();
  }
  float linv = 1.0f / lreg;
  float invr[4];
#pragma unroll
  for (int r = 0; r < 4; r++)
    invr[r] = __shfl(linv, (lane & 48) | (g * 4 + r), 64);
#pragma unroll
  for (int nd = 0; nd < 4; nd++)
#pragma unroll
    for (int r = 0; r < 4; r++)
      O[(size_t)b * SEQ * EMB + (size_t)(qb + w * 16 + g * 4 + r) * EMB + h * 64 + nd * 16 + li] =
          f2b(o[nd][r] * invr[r]);
}

// ---------------- LayerNorm (one wave per 512-row), fp32 + optional bf16 out ----
__global__ __launch_bounds__(256) void ln_fused(
    const float* __restrict__ in, const float* __restrict__ gamma,
    const float* __restrict__ beta, float* __restrict__ outf, u16* __restrict__ outb) {
  int row = blockIdx.x * 4 + (threadIdx.x >> 6);
  int lane = threadIdx.x & 63;
  const float* p = in + (size_t)row * EMB + lane * 8;
  float v[8];
  *(float4*)&v[0] = *(const float4*)p;
  *(float4*)&v[4] = *(const float4*)(p + 4);
  float s = 0.f, q = 0.f;
#pragma unroll
  for (int j = 0; j < 8; j++) { s += v[j]; q += v[j] * v[j]; }
#pragma unroll
  for (int d = 1; d < 64; d <<= 1) {
    s += __shfl_xor(s, d, 64);
    q += __shfl_xor(q, d, 64);
  }
  float mu = s * (1.0f / EMB);
  float var = q * (1.0f / EMB) - mu * mu;
  float rsig = rsqrtf(var + 1e-5f);
  float gg[8], bb[8];
  *(float4*)&gg[0] = *(const float4*)(gamma + lane * 8);
  *(float4*)&gg[4] = *(const float4*)(gamma + lane * 8 + 4);
  *(float4*)&bb[0] = *(const float4*)(beta + lane * 8);
  *(float4*)&bb[4] = *(const float4*)(beta + lane * 8 + 4);
  float o[8];
#pragma unroll
  for (int j = 0; j < 8; j++) o[j] = (v[j] - mu) * rsig * gg[j] + bb[j];
  float* po = outf + (size_t)row * EMB + lane * 8;
  *(float4*)po = *(float4*)&o[0];
  *(float4*)(po + 4) = *(float4*)&o[4];
  if (outb) {
    uint4 u;
    u.x = f2b(o[0]) | ((unsigned)f2b(o[1]) << 16);
    u.y = f2b(o[2]) | ((unsigned)f2b(o[3]) << 16);
    u.z = f2b(o[4]) | ((unsigned)f2b(o[5]) << 16);
    u.w = f2b(o[6]) | ((unsigned)f2b(o[7]) << 16);
    *(uint4*)(outb + (size_t)row * EMB + lane * 8) = u;
  }
}

extern "C" void kernel_launch(void* const* d_in, const int* in_sizes, int n_in,
                              void* d_out, int out_size, void* d_ws, size_t ws_size,
                              hipStream_t stream) {
  const float* x     = (const float*)d_in[0];
  const float* enc   = (const float*)d_in[1];
  const float* sa_wq = (const float*)d_in[2];
  const float* sa_bq = (const float*)d_in[3];
  const float* sa_wk = (const float*)d_in[4];
  const float* sa_bk = (const float*)d_in[5];
  const float* sa_wv = (const float*)d_in[6];
  const float* sa_bv = (const float*)d_in[7];
  const float* sa_wo = (const float*)d_in[8];
  const float* sa_bo = (const float*)d_in[9];
  const float* ca_wq = (const float*)d_in[10];
  const float* ca_bq = (const float*)d_in[11];
  const float* ca_wk = (const float*)d_in[12];
  const float* ca_bk = (const float*)d_in[13];
  const float* ca_wv = (const float*)d_in[14];
  const float* ca_bv = (const float*)d_in[15];
  const float* ca_wo = (const float*)d_in[16];
  const float* ca_bo = (const float*)d_in[17];
  const float* ln1_g = (const float*)d_in[18];
  const float* ln1_b = (const float*)d_in[19];
  const float* ln2_g = (const float*)d_in[20];
  const float* ln2_b = (const float*)d_in[21];
  const float* ln3_g = (const float*)d_in[22];
  const float* ln3_b = (const float*)d_in[23];
  const float* ff_w1 = (const float*)d_in[24];
  const float* ff_b1 = (const float*)d_in[25];
  const float* ff_w2 = (const float*)d_in[26];
  const float* ff_b2 = (const float*)d_in[27];

  char* ws = (char*)d_ws;
  size_t off = 0;
  auto alloc = [&](size_t bytes) {
    void* p = ws + off;
    off = (off + bytes + 255) & ~(size_t)255;
    return p;
  };
  u16* qkvT_sa  = (u16*)alloc((size_t)1536 * EMB * 2);
  u16* oT_sa    = (u16*)alloc((size_t)EMB * EMB * 2);
  u16* qT_ca    = (u16*)alloc((size_t)EMB * EMB * 2);
  u16* kvT_ca   = (u16*)alloc((size_t)1024 * EMB * 2);
  u16* oT_ca    = (u16*)alloc((size_t)EMB * EMB * 2);
  u16* w1T      = (u16*)alloc((size_t)FF * EMB * 2);
  u16* w2T      = (u16*)alloc((size_t)EMB * FF * 2);
  float* bqkv_sa = (float*)alloc(1536 * 4);
  float* bkv_ca  = (float*)alloc(1024 * 4);
  u16* xb    = (u16*)alloc((size_t)MTOT * EMB * 2);
  u16* encb  = (u16*)alloc((size_t)MTOT * EMB * 2);
  u16* qkv   = (u16*)alloc((size_t)MTOT * 1536 * 2);
  u16* attnb = (u16*)alloc((size_t)MTOT * EMB * 2);
  float* t0  = (float*)alloc((size_t)MTOT * EMB * 4);
  float* x1  = (float*)alloc((size_t)MTOT * EMB * 4);
  u16* x1b   = (u16*)alloc((size_t)MTOT * EMB * 2);
  float* x2  = (float*)alloc((size_t)MTOT * EMB * 4);
  u16* x2b   = (u16*)alloc((size_t)MTOT * EMB * 2);
  u16* hbuf  = (u16*)alloc((size_t)MTOT * FF * 2);
  u16* qca  = xb;   // xb dead after SA-QKV gemm
  u16* kvca = qkv;  // qkv dead after SA attention

  prep_all<<<dim3(64, 16, 12), 256, 0, stream>>>(
      sa_wq, sa_wk, sa_wv, sa_wo, ca_wq, ca_wk, ca_wv, ca_wo, ff_w1, ff_w2,
      qkvT_sa, qkvT_sa + 512 * EMB, qkvT_sa + 1024 * EMB, oT_sa, qT_ca,
      kvT_ca, kvT_ca + 512 * EMB, oT_ca, w1T, w2T,
      x, xb, enc, encb,
      sa_bq, sa_bk, sa_bv, bqkv_sa, ca_bk, ca_bv, bkv_ca);

  // ---- self-attention block ----
  gemm_bt<128, 64, true, false, false, false><<<dim3(32, 24), 256, 0, stream>>>(
      xb, qkvT_sa, bqkv_sa, nullptr, qkv, nullptr, EMB, 1536);
  attn_fwd<true><<<512, 256, 0, stream>>>(qkv, qkv + 512, qkv + 1024, attnb, 1536, 1536);
  gemm_bt<64, 64, false, true, true, false><<<dim3(64, 8), 256, 0, stream>>>(
      attnb, oT_sa, sa_bo, x, nullptr, t0, EMB, EMB);
  ln_fused<<<1024, 256, 0, stream>>>(t0, ln1_g, ln1_b, x1, x1b);

  // ---- cross-attention block ----
  gemm_bt<64, 64, true, false, false, false><<<dim3(64, 8), 256, 0, stream>>>(
      x1b, qT_ca, ca_bq, nullptr, qca, nullptr, EMB, EMB);
  gemm_bt<128, 64, true, false, false, false><<<dim3(32, 16), 256, 0, stream>>>(
      encb, kvT_ca, bkv_ca, nullptr, kvca, nullptr, EMB, 1024);
  attn_fwd<false><<<512, 256, 0, stream>>>(qca, kvca, kvca + 512, attnb, EMB, 1024);
  gemm_bt<64, 64, false, true, true, false><<<dim3(64, 8), 256, 0, stream>>>(
      attnb, oT_ca, ca_bo, x1, nullptr, t0, EMB, EMB);
  ln_fused<<<1024, 256, 0, stream>>>(t0, ln2_g, ln2_b, x2, x2b);

  // ---- FFN block ----
  gemm_bt<128, 128, true, false, false, true><<<dim3(32, 16), 256, 0, stream>>>(
      x2b, w1T, ff_b1, nullptr, hbuf, nullptr, EMB, FF);
  gemm_bt<64, 64, false, true, true, false><<<dim3(64, 8), 256, 0, stream>>>(
      hbuf, w2T, ff_b2, x2, nullptr, t0, FF, EMB);
  ln_fused<<<1024, 256, 0, stream>>>(t0, ln3_g, ln3_b, (float*)d_out, nullptr);
}

// Round 5
// 325.715 us; speedup vs baseline: 1.6583x; 1.0428x over previous
//
#include <hip/hip_runtime.h>
#include <hip/hip_bf16.h>

typedef __bf16 bf16x8 __attribute__((ext_vector_type(8)));
typedef float f32x4 __attribute__((ext_vector_type(4)));
typedef unsigned short u16;

#define EMB 512
#define FF 2048
#define MTOT 4096
#define SEQ 2048

__device__ __forceinline__ u16 f2b(float f) {
  return __builtin_bit_cast(u16, (__bf16)f);
}

__device__ __forceinline__ void gload16(const u16* g, u16* l) {
  __builtin_amdgcn_global_load_lds(
      (const __attribute__((address_space(1))) unsigned int*)g,
      (__attribute__((address_space(3))) unsigned int*)l, 16, 0, 0);
}

template <int N>
__device__ __forceinline__ void wait_vmcnt() {
  if constexpr (N == 0) asm volatile("s_waitcnt vmcnt(0)" ::: "memory");
  else if constexpr (N == 4) asm volatile("s_waitcnt vmcnt(4)" ::: "memory");
  else if constexpr (N == 6) asm volatile("s_waitcnt vmcnt(6)" ::: "memory");
  else if constexpr (N == 8) asm volatile("s_waitcnt vmcnt(8)" ::: "memory");
}

// ---------------- fused prep: 10 weight transposes + 2 cvt + 2 bias concats ----
__global__ __launch_bounds__(256) void prep_all(
    const float* s0, const float* s1, const float* s2, const float* s3,
    const float* s4, const float* s5, const float* s6, const float* s7,
    const float* s8, const float* s9,
    u16* d0, u16* d1, u16* d2, u16* d3, u16* d4,
    u16* d5, u16* d6, u16* d7, u16* d8, u16* d9,
    const float* x, u16* xb, const float* enc, u16* encb,
    const float* bq1, const float* bk1, const float* bv1, float* bqkv,
    const float* bk2, const float* bv2, float* bkv) {
  int z = blockIdx.z, bx = blockIdx.x, by = blockIdx.y;
  int tid = threadIdx.x;
  if (z >= 10) {  // fp32 -> bf16 cvt of x / enc
    int fb = by * 64 + bx;
    const float* src = (z == 10) ? x : enc;
    u16* dst = (z == 10) ? xb : encb;
    size_t base = (size_t)fb * 2048 + tid * 8;
    float4 a = *(const float4*)(src + base);
    float4 b = *(const float4*)(src + base + 4);
    uint4 u;
    u.x = f2b(a.x) | ((unsigned)f2b(a.y) << 16);
    u.y = f2b(a.z) | ((unsigned)f2b(a.w) << 16);
    u.z = f2b(b.x) | ((unsigned)f2b(b.y) << 16);
    u.w = f2b(b.z) | ((unsigned)f2b(b.w) << 16);
    *(uint4*)(dst + base) = u;
    return;
  }
  if (z == 0 && bx == 16 && by == 0) {
    for (int i = tid; i < 1536; i += 256)
      bqkv[i] = (i < 512) ? bq1[i] : (i < 1024 ? bk1[i - 512] : bv1[i - 1024]);
    return;
  }
  if (z == 1 && bx == 16 && by == 0) {
    for (int i = tid; i < 1024; i += 256)
      bkv[i] = (i < 512) ? bk2[i] : bv2[i - 512];
    return;
  }
  const float* src; u16* dst; int K, N;
  switch (z) {
    case 0: src = s0; dst = d0; K = 512; N = 512; break;
    case 1: src = s1; dst = d1; K = 512; N = 512; break;
    case 2: src = s2; dst = d2; K = 512; N = 512; break;
    case 3: src = s3; dst = d3; K = 512; N = 512; break;
    case 4: src = s4; dst = d4; K = 512; N = 512; break;
    case 5: src = s5; dst = d5; K = 512; N = 512; break;
    case 6: src = s6; dst = d6; K = 512; N = 512; break;
    case 7: src = s7; dst = d7; K = 512; N = 512; break;
    case 8: src = s8; dst = d8; K = 512; N = 2048; break;
    default: src = s9; dst = d9; K = 2048; N = 512; break;
  }
  int ntl, ktl;
  if (z == 9) { ktl = bx; ntl = by; } else { ntl = bx; ktl = by; }
  if (ntl * 32 >= N || ktl * 32 >= K) return;
  __shared__ float t[32][33];
  int tx = tid & 31, ty = tid >> 5;
  int n0 = ntl * 32, k0 = ktl * 32;
#pragma unroll
  for (int i = 0; i < 4; i++)
    t[ty + i * 8][tx] = src[(size_t)(k0 + ty + i * 8) * N + n0 + tx];
  __syncthreads();
#pragma unroll
  for (int i = 0; i < 4; i++)
    dst[(size_t)(n0 + ty + i * 8) * K + k0 + tx] = f2b(t[tx][ty + i * 8]);
}

// ---- bf16 GEMM: BK=64, counted-vmcnt 2-barrier pipeline, global_load_lds ----
// C[M,Nd] = A[M,K] @ Bt[Nd,K]^T + bias (+res,+gelu). BMxBN tile, 4 waves (2x2).
template <int BM, int BN, bool OUTB, bool OUTF, bool RES, bool GELU_>
__global__ __launch_bounds__(256) void gemm_bt(
    const u16* __restrict__ A, const u16* __restrict__ Bt,
    const float* __restrict__ bias, const float* __restrict__ resid,
    u16* __restrict__ outb, float* __restrict__ outf, int K, int Nd) {
  constexpr int MI = BM / 32;      // per-wave M fragments (wave tile BM/2)
  constexpr int NI = BN / 32;      // per-wave N fragments (wave tile BN/2)
  constexpr int RA = BM / 32;      // A staging gloads/thread (BM*8 chunks / 256)
  constexpr int RB = BN / 32;      // B staging gloads/thread
  constexpr int L = RA + RB;       // vmcnt per stage
  __shared__ u16 As[2][BM * 64];
  __shared__ u16 Bs[2][BN * 64];
  int tid = threadIdx.x;
  int lane = tid & 63, w = tid >> 6;
  int g = lane >> 4, li = lane & 15;
  int wr = w >> 1, wc = w & 1;
  int m0 = blockIdx.x * BM, n0 = blockIdx.y * BN;
  // staging: chunk c = r*256+tid -> row = c>>3, ch = c&7; LDS lane-linear at c*16B.
  // LDS(row,ch) holds global chunk ch^(row&7)  [involution swizzle]
  int row_s = tid >> 3, ch_s = tid & 7;
  const u16* srcs[L];
  int ldsoff[L];
#pragma unroll
  for (int r = 0; r < L; r++) {
    int rr = (r < RA) ? r : r - RA;
    int row = rr * 32 + row_s;
    int csw = ch_s ^ (row & 7);
    srcs[r] = ((r < RA) ? A + (size_t)(m0 + row) * K : Bt + (size_t)(n0 + row) * K) + csw * 8;
    ldsoff[r] = (rr * 256 + tid) * 8;
  }
  f32x4 acc[MI][NI] = {};
  int T = K >> 6;
  auto stage = [&](int t, int buf) {
    int k0 = t << 6;
#pragma unroll
    for (int r = 0; r < RA; r++) gload16(srcs[r] + k0, &As[buf][ldsoff[r]]);
#pragma unroll
    for (int r = RA; r < L; r++) gload16(srcs[r] + k0, &Bs[buf][ldsoff[r]]);
  };
  stage(0, 0);
  stage(1, 1);
  for (int t = 0; t < T; t++) {
    int cur = t & 1;
    if (t == T - 1) wait_vmcnt<0>(); else wait_vmcnt<L>();
    __builtin_amdgcn_s_barrier();
    __builtin_amdgcn_sched_barrier(0);
    bf16x8 af[MI][2], bfr[NI][2];
#pragma unroll
    for (int i = 0; i < MI; i++) {
      int R = wr * (BM / 2) + i * 16 + li;
#pragma unroll
      for (int ks = 0; ks < 2; ks++)
        af[i][ks] = *(const bf16x8*)&As[cur][R * 64 + (((ks * 4 + g) ^ (R & 7)) * 8)];
    }
#pragma unroll
    for (int i = 0; i < NI; i++) {
      int R = wc * (BN / 2) + i * 16 + li;
#pragma unroll
      for (int ks = 0; ks < 2; ks++)
        bfr[i][ks] = *(const bf16x8*)&Bs[cur][R * 64 + (((ks * 4 + g) ^ (R & 7)) * 8)];
    }
#pragma unroll
    for (int mi = 0; mi < MI; mi++)
#pragma unroll
      for (int ni = 0; ni < NI; ni++)
#pragma unroll
        for (int ks = 0; ks < 2; ks++)
          acc[mi][ni] = __builtin_amdgcn_mfma_f32_16x16x32_bf16(af[mi][ks], bfr[ni][ks], acc[mi][ni], 0, 0, 0);
    __builtin_amdgcn_s_barrier();
    if (t + 2 < T) stage(t + 2, cur);
  }
#pragma unroll
  for (int mi = 0; mi < MI; mi++)
#pragma unroll
    for (int ni = 0; ni < NI; ni++) {
      int gn = n0 + wc * (BN / 2) + ni * 16 + li;
      float bv = bias[gn];
#pragma unroll
      for (int r = 0; r < 4; r++) {
        int gm = m0 + wr * (BM / 2) + mi * 16 + g * 4 + r;
        float v = acc[mi][ni][r] + bv;
        if (RES) v += resid[(size_t)gm * Nd + gn];
        if (GELU_) v = 0.5f * v * (1.0f + erff(v * 0.70710678118654752f));
        if (OUTF) outf[(size_t)gm * Nd + gn] = v;
        if (OUTB) outb[(size_t)gm * Nd + gn] = f2b(v);
      }
    }
}

// ---------------- flash attention: KVBLK=128, dbuf, exp2-domain, defer-max ----
// grid 512 flat: bh = idx&15, qb-block(64) = idx>>4. 4 waves x 16 q.
template <bool CAUSAL>
__global__ __launch_bounds__(256) void attn_fwd(
    const u16* __restrict__ Q, const u16* __restrict__ Kp,
    const u16* __restrict__ Vp, u16* __restrict__ O, int qs, int kvs) {
  __shared__ u16 Ks[2][128 * 64];   // [key][d] rows 64, chunk-swizzled
  __shared__ u16 Vt[2][64 * 128];   // [d][key] rows 128, chunk-swizzled
  __shared__ u16 Ps[4][16 * 128];   // per-wave P [q][key]
  int tid = threadIdx.x;
  int lane = tid & 63, w = tid >> 6;
  int g = lane >> 4, li = lane & 15;
  int idx = blockIdx.x;
  int bh = idx & 15;
  int qbi = idx >> 4;
  if (CAUSAL) qbi = (SEQ / 64 - 1) - qbi;  // heavy first
  int qb = qbi * 64;
  int b = bh >> 3, h = bh & 7;
  const u16* Qh = Q + (size_t)b * SEQ * qs + h * 64;
  const u16* Kh = Kp + (size_t)b * SEQ * kvs + h * 64;
  const u16* Vh = Vp + (size_t)b * SEQ * kvs + h * 64;
  int qrow = qb + w * 16 + li;
  // Q fragment, pre-scaled by log2(e)/sqrt(64) -> softmax in exp2 domain
  bf16x8 qa[2];
#pragma unroll
  for (int ks = 0; ks < 2; ks++) {
    bf16x8 tq = *(const bf16x8*)&Qh[(size_t)qrow * qs + ks * 32 + g * 8];
#pragma unroll
    for (int j = 0; j < 8; j++) tq[j] = (__bf16)((float)tq[j] * 0.18033688011112042f);
    qa[ks] = tq;
  }
  // K staging via global_load_lds: 4 gloads/thread, lane-linear dest
  int kcc = lane & 7;
  const u16* Ksrc[4];
#pragma unroll
  for (int j = 0; j < 4; j++) {
    int row = j * 32 + w * 8 + (lane >> 3);
    int sw = ((j * 4 + w) ^ (lane >> 3)) & 7;
    Ksrc[j] = Kh + (size_t)row * kvs + (kcc ^ sw) * 8;
  }
  size_t kstep = (size_t)128 * kvs;
  // V staging: thread owns keys 4*kq..+3, d-chunk dcv
  int kq = tid & 31, dcv = tid >> 5;
  const u16* Vsrc = Vh + (size_t)(4 * kq) * kvs + dcv * 8;
  uint4 vr[4];
  auto stageK = [&](int t, int buf) {
    size_t o = (size_t)t * kstep;
    u16* dst = &Ks[buf][w * 512];
#pragma unroll
    for (int j = 0; j < 4; j++) gload16(Ksrc[j] + o, dst + j * 2048);
  };
  auto loadV = [&](int t) {
    size_t o = (size_t)t * kstep;
#pragma unroll
    for (int kk = 0; kk < 4; kk++)
      vr[kk] = *(const uint4*)(Vsrc + o + (size_t)kk * kvs);
  };
  auto writeV = [&](int buf) {
    const u16* a0 = (const u16*)&vr[0];
    const u16* a1 = (const u16*)&vr[1];
    const u16* a2 = (const u16*)&vr[2];
    const u16* a3 = (const u16*)&vr[3];
#pragma unroll
    for (int jj = 0; jj < 8; jj++) {
      int d = dcv * 8 + jj;
      int swv = ((d >> 3) ^ d) & 15;
      uint2 pk;
      pk.x = (unsigned)a0[jj] | ((unsigned)a1[jj] << 16);
      pk.y = (unsigned)a2[jj] | ((unsigned)a3[jj] << 16);
      *(uint2*)&Vt[buf][d * 128 + ((kq >> 1) ^ swv) * 8 + 4 * (kq & 1)] = pk;
    }
  };
  int T = CAUSAL ? (qb >> 7) + 1 : SEQ / 128;
  stageK(0, 0);
  loadV(0);
  writeV(0);
  __syncthreads();
  f32x4 o[4] = {};
  float mreg = -1e30f, lreg = 0.f;
  for (int t = 0; t < T; t++) {
    int cur = t & 1;
    if (t + 1 < T) { stageK(t + 1, cur ^ 1); loadV(t + 1); }
    int kv0 = t << 7;
    // S^T = K.Q^T : lane holds S[k = kv0+nt*16+g*4+r][q = li]
    f32x4 S[8] = {};
    __builtin_amdgcn_s_setprio(1);
#pragma unroll
    for (int nt = 0; nt < 8; nt++) {
      int krow = nt * 16 + li;
      int sw = ((krow >> 3) ^ krow) & 7;
#pragma unroll
      for (int ks = 0; ks < 2; ks++) {
        bf16x8 kb = *(const bf16x8*)&Ks[cur][krow * 64 + ((ks * 4 + g) ^ sw) * 8];
        S[nt] = __builtin_amdgcn_mfma_f32_16x16x32_bf16(kb, qa[ks], S[nt], 0, 0, 0);
      }
    }
    __builtin_amdgcn_s_setprio(0);
    if (CAUSAL && (kv0 + 127 > qb + w * 16)) {  // wave-uniform boundary test
#pragma unroll
      for (int nt = 0; nt < 8; nt++) {
        int kb0 = kv0 + nt * 16 + g * 4;
#pragma unroll
        for (int r = 0; r < 4; r++)
          if (kb0 + r > qrow) S[nt][r] = -1e30f;
      }
    }
    f32x4 mx = S[0];
#pragma unroll
    for (int nt = 1; nt < 8; nt++)
#pragma unroll
      for (int r = 0; r < 4; r++) mx[r] = fmaxf(mx[r], S[nt][r]);
    float pm = fmaxf(fmaxf(mx[0], mx[1]), fmaxf(mx[2], mx[3]));
    pm = fmaxf(pm, __shfl_xor(pm, 16, 64));
    pm = fmaxf(pm, __shfl_xor(pm, 32, 64));
    bool need = __any(pm > mreg + 8.0f);  // defer-max: P bounded by 2^8
    float nm = need ? fmaxf(mreg, pm) : mreg;
    f32x4 acc4 = {0.f, 0.f, 0.f, 0.f};
#pragma unroll
    for (int nt = 0; nt < 8; nt++)
#pragma unroll
      for (int r = 0; r < 4; r++) {
        float e = exp2f(S[nt][r] - nm);
        S[nt][r] = e;
        acc4[r] += e;
      }
    float rs = (acc4[0] + acc4[1]) + (acc4[2] + acc4[3]);
    rs += __shfl_xor(rs, 16, 64);
    rs += __shfl_xor(rs, 32, 64);
    if (need) {
      float csc = exp2f(mreg - nm);
      lreg = lreg * csc + rs;
      mreg = nm;
      float cscr[4];
#pragma unroll
      for (int r = 0; r < 4; r++)
        cscr[r] = __shfl(csc, (lane & 48) | (g * 4 + r), 64);
#pragma unroll
      for (int nd = 0; nd < 4; nd++)
#pragma unroll
        for (int r = 0; r < 4; r++) o[nd][r] *= cscr[r];
    } else {
      lreg += rs;
    }
    // P -> per-wave LDS as b64 (bank-balanced)
#pragma unroll
    for (int nt = 0; nt < 8; nt++) {
      int cp = 2 * nt + (g >> 1);
      uint2 pk;
      pk.x = (unsigned)f2b(S[nt][0]) | ((unsigned)f2b(S[nt][1]) << 16);
      pk.y = (unsigned)f2b(S[nt][2]) | ((unsigned)f2b(S[nt][3]) << 16);
      *(uint2*)&Ps[w][li * 128 + ((cp ^ li) * 8) + 4 * (g & 1)] = pk;
    }
    bf16x8 pa[4];
#pragma unroll
    for (int k2 = 0; k2 < 4; k2++)
      pa[k2] = *(const bf16x8*)&Ps[w][li * 128 + (((k2 * 4 + g) ^ li) * 8)];
    __builtin_amdgcn_s_setprio(1);
#pragma unroll
    for (int nd = 0; nd < 4; nd++) {
      int d = nd * 16 + li;
      int swv = ((d >> 3) ^ d) & 15;
#pragma unroll
      for (int k2 = 0; k2 < 4; k2++) {
        bf16x8 vb = *(const bf16x8*)&Vt[cur][d * 128 + (((k2 * 4 + g) ^ swv) * 8)];
        o[nd] = __builtin_amdgcn_mfma_f32_16x16x32_bf16(pa[k2], vb, o[nd], 0, 0, 0);
      }
    }
    __builtin_amdgcn_s_setprio(0);
    if (t + 1 < T) writeV(cur ^ 1);
    __syncthreads();
  }
  float linv = 1.0f / lreg;
  float invr[4];
#pragma unroll
  for (int r = 0; r < 4; r++)
    invr[r] = __shfl(linv, (lane & 48) | (g * 4 + r), 64);
#pragma unroll
  for (int nd = 0; nd < 4; nd++)
#pragma unroll
    for (int r = 0; r < 4; r++)
      O[(size_t)b * SEQ * EMB + (size_t)(qb + w * 16 + g * 4 + r) * EMB + h * 64 + nd * 16 + li] =
          f2b(o[nd][r] * invr[r]);
}

// ---------------- LayerNorm (one wave per 512-row), fp32 + optional bf16 out ----
__global__ __launch_bounds__(256) void ln_fused(
    const float* __restrict__ in, const float* __restrict__ gamma,
    const float* __restrict__ beta, float* __restrict__ outf, u16* __restrict__ outb) {
  int row = blockIdx.x * 4 + (threadIdx.x >> 6);
  int lane = threadIdx.x & 63;
  const float* p = in + (size_t)row * EMB + lane * 8;
  float v[8];
  *(float4*)&v[0] = *(const float4*)p;
  *(float4*)&v[4] = *(const float4*)(p + 4);
  float s = 0.f, q = 0.f;
#pragma unroll
  for (int j = 0; j < 8; j++) { s += v[j]; q += v[j] * v[j]; }
#pragma unroll
  for (int d = 1; d < 64; d <<= 1) {
    s += __shfl_xor(s, d, 64);
    q += __shfl_xor(q, d, 64);
  }
  float mu = s * (1.0f / EMB);
  float var = q * (1.0f / EMB) - mu * mu;
  float rsig = rsqrtf(var + 1e-5f);
  float gg[8], bb[8];
  *(float4*)&gg[0] = *(const float4*)(gamma + lane * 8);
  *(float4*)&gg[4] = *(const float4*)(gamma + lane * 8 + 4);
  *(float4*)&bb[0] = *(const float4*)(beta + lane * 8);
  *(float4*)&bb[4] = *(const float4*)(beta + lane * 8 + 4);
  float o[8];
#pragma unroll
  for (int j = 0; j < 8; j++) o[j] = (v[j] - mu) * rsig * gg[j] + bb[j];
  float* po = outf + (size_t)row * EMB + lane * 8;
  *(float4*)po = *(float4*)&o[0];
  *(float4*)(po + 4) = *(float4*)&o[4];
  if (outb) {
    uint4 u;
    u.x = f2b(o[0]) | ((unsigned)f2b(o[1]) << 16);
    u.y = f2b(o[2]) | ((unsigned)f2b(o[3]) << 16);
    u.z = f2b(o[4]) | ((unsigned)f2b(o[5]) << 16);
    u.w = f2b(o[6]) | ((unsigned)f2b(o[7]) << 16);
    *(uint4*)(outb + (size_t)row * EMB + lane * 8) = u;
  }
}

extern "C" void kernel_launch(void* const* d_in, const int* in_sizes, int n_in,
                              void* d_out, int out_size, void* d_ws, size_t ws_size,
                              hipStream_t stream) {
  const float* x     = (const float*)d_in[0];
  const float* enc   = (const float*)d_in[1];
  const float* sa_wq = (const float*)d_in[2];
  const float* sa_bq = (const float*)d_in[3];
  const float* sa_wk = (const float*)d_in[4];
  const float* sa_bk = (const float*)d_in[5];
  const float* sa_wv = (const float*)d_in[6];
  const float* sa_bv = (const float*)d_in[7];
  const float* sa_wo = (const float*)d_in[8];
  const float* sa_bo = (const float*)d_in[9];
  const float* ca_wq = (const float*)d_in[10];
  const float* ca_bq = (const float*)d_in[11];
  const float* ca_wk = (const float*)d_in[12];
  const float* ca_bk = (const float*)d_in[13];
  const float* ca_wv = (const float*)d_in[14];
  const float* ca_bv = (const float*)d_in[15];
  const float* ca_wo = (const float*)d_in[16];
  const float* ca_bo = (const float*)d_in[17];
  const float* ln1_g = (const float*)d_in[18];
  const float* ln1_b = (const float*)d_in[19];
  const float* ln2_g = (const float*)d_in[20];
  const float* ln2_b = (const float*)d_in[21];
  const float* ln3_g = (const float*)d_in[22];
  const float* ln3_b = (const float*)d_in[23];
  const float* ff_w1 = (const float*)d_in[24];
  const float* ff_b1 = (const float*)d_in[25];
  const float* ff_w2 = (const float*)d_in[26];
  const float* ff_b2 = (const float*)d_in[27];

  char* ws = (char*)d_ws;
  size_t off = 0;
  auto alloc = [&](size_t bytes) {
    void* p = ws + off;
    off = (off + bytes + 255) & ~(size_t)255;
    return p;
  };
  u16* qkvT_sa  = (u16*)alloc((size_t)1536 * EMB * 2);
  u16* oT_sa    = (u16*)alloc((size_t)EMB * EMB * 2);
  u16* qT_ca    = (u16*)alloc((size_t)EMB * EMB * 2);
  u16* kvT_ca   = (u16*)alloc((size_t)1024 * EMB * 2);
  u16* oT_ca    = (u16*)alloc((size_t)EMB * EMB * 2);
  u16* w1T      = (u16*)alloc((size_t)FF * EMB * 2);
  u16* w2T      = (u16*)alloc((size_t)EMB * FF * 2);
  float* bqkv_sa = (float*)alloc(1536 * 4);
  float* bkv_ca  = (float*)alloc(1024 * 4);
  u16* xb    = (u16*)alloc((size_t)MTOT * EMB * 2);
  u16* encb  = (u16*)alloc((size_t)MTOT * EMB * 2);
  u16* qkv   = (u16*)alloc((size_t)MTOT * 1536 * 2);
  u16* attnb = (u16*)alloc((size_t)MTOT * EMB * 2);
  float* t0  = (float*)alloc((size_t)MTOT * EMB * 4);
  float* x1  = (float*)alloc((size_t)MTOT * EMB * 4);
  u16* x1b   = (u16*)alloc((size_t)MTOT * EMB * 2);
  float* x2  = (float*)alloc((size_t)MTOT * EMB * 4);
  u16* x2b   = (u16*)alloc((size_t)MTOT * EMB * 2);
  u16* hbuf  = (u16*)alloc((size_t)MTOT * FF * 2);
  u16* qca  = xb;   // xb dead after SA-QKV gemm
  u16* kvca = qkv;  // qkv dead after SA attention

  prep_all<<<dim3(64, 16, 12), 256, 0, stream>>>(
      sa_wq, sa_wk, sa_wv, sa_wo, ca_wq, ca_wk, ca_wv, ca_wo, ff_w1, ff_w2,
      qkvT_sa, qkvT_sa + 512 * EMB, qkvT_sa + 1024 * EMB, oT_sa, qT_ca,
      kvT_ca, kvT_ca + 512 * EMB, oT_ca, w1T, w2T,
      x, xb, enc, encb,
      sa_bq, sa_bk, sa_bv, bqkv_sa, ca_bk, ca_bv, bkv_ca);

  // ---- self-attention block ----
  gemm_bt<128, 64, true, false, false, false><<<dim3(32, 24), 256, 0, stream>>>(
      xb, qkvT_sa, bqkv_sa, nullptr, qkv, nullptr, EMB, 1536);
  attn_fwd<true><<<512, 256, 0, stream>>>(qkv, qkv + 512, qkv + 1024, attnb, 1536, 1536);
  gemm_bt<64, 64, false, true, true, false><<<dim3(64, 8), 256, 0, stream>>>(
      attnb, oT_sa, sa_bo, x, nullptr, t0, EMB, EMB);
  ln_fused<<<1024, 256, 0, stream>>>(t0, ln1_g, ln1_b, x1, x1b);

  // ---- cross-attention block ----
  gemm_bt<64, 64, true, false, false, false><<<dim3(64, 8), 256, 0, stream>>>(
      x1b, qT_ca, ca_bq, nullptr, qca, nullptr, EMB, EMB);
  gemm_bt<128, 64, true, false, false, false><<<dim3(32, 16), 256, 0, stream>>>(
      encb, kvT_ca, bkv_ca, nullptr, kvca, nullptr, EMB, 1024);
  attn_fwd<false><<<512, 256, 0, stream>>>(qca, kvca, kvca + 512, attnb, EMB, 1024);
  gemm_bt<64, 64, false, true, true, false><<<dim3(64, 8), 256, 0, stream>>>(
      attnb, oT_ca, ca_bo, x1, nullptr, t0, EMB, EMB);
  ln_fused<<<1024, 256, 0, stream>>>(t0, ln2_g, ln2_b, x2, x2b);

  // ---- FFN block ----
  gemm_bt<128, 64, true, false, false, true><<<dim3(32, 32), 256, 0, stream>>>(
      x2b, w1T, ff_b1, nullptr, hbuf, nullptr, EMB, FF);
  gemm_bt<64, 64, false, true, true, false><<<dim3(64, 8), 256, 0, stream>>>(
      hbuf, w2T, ff_b2, x2, nullptr, t0, FF, EMB);
  ln_fused<<<1024, 256, 0, stream>>>(t0, ln3_g, ln3_b, (float*)d_out, nullptr);
}

// Round 6
// 325.466 us; speedup vs baseline: 1.6596x; 1.0008x over previous
//
#include <hip/hip_runtime.h>
#include <hip/hip_bf16.h>

typedef __bf16 bf16x8 __attribute__((ext_vector_type(8)));
typedef float f32x4 __attribute__((ext_vector_type(4)));
typedef unsigned short u16;

#define EMB 512
#define FF 2048
#define MTOT 4096
#define SEQ 2048

__device__ __forceinline__ u16 f2b(float f) {
  return __builtin_bit_cast(u16, (__bf16)f);
}

__device__ __forceinline__ void gload16(const u16* g, u16* l) {
  __builtin_amdgcn_global_load_lds(
      (const __attribute__((address_space(1))) unsigned int*)g,
      (__attribute__((address_space(3))) unsigned int*)l, 16, 0, 0);
}

template <int N>
__device__ __forceinline__ void wait_vmcnt() {
  if constexpr (N == 0) asm volatile("s_waitcnt vmcnt(0)" ::: "memory");
  else if constexpr (N == 4) asm volatile("s_waitcnt vmcnt(4)" ::: "memory");
  else if constexpr (N == 6) asm volatile("s_waitcnt vmcnt(6)" ::: "memory");
  else if constexpr (N == 8) asm volatile("s_waitcnt vmcnt(8)" ::: "memory");
}

// ---------------- fused prep: 10 weight transposes + 2 cvt + 2 bias concats ----
__global__ __launch_bounds__(256) void prep_all(
    const float* s0, const float* s1, const float* s2, const float* s3,
    const float* s4, const float* s5, const float* s6, const float* s7,
    const float* s8, const float* s9,
    u16* d0, u16* d1, u16* d2, u16* d3, u16* d4,
    u16* d5, u16* d6, u16* d7, u16* d8, u16* d9,
    const float* x, u16* xb, const float* enc, u16* encb,
    const float* bq1, const float* bk1, const float* bv1, float* bqkv,
    const float* bq2, const float* bk2, const float* bv2, float* bca) {
  int z = blockIdx.z, bx = blockIdx.x, by = blockIdx.y;
  int tid = threadIdx.x;
  if (z >= 10) {  // fp32 -> bf16 cvt of x / enc
    int fb = by * 64 + bx;
    const float* src = (z == 10) ? x : enc;
    u16* dst = (z == 10) ? xb : encb;
    size_t base = (size_t)fb * 2048 + tid * 8;
    float4 a = *(const float4*)(src + base);
    float4 b = *(const float4*)(src + base + 4);
    uint4 u;
    u.x = f2b(a.x) | ((unsigned)f2b(a.y) << 16);
    u.y = f2b(a.z) | ((unsigned)f2b(a.w) << 16);
    u.z = f2b(b.x) | ((unsigned)f2b(b.y) << 16);
    u.w = f2b(b.z) | ((unsigned)f2b(b.w) << 16);
    *(uint4*)(dst + base) = u;
    return;
  }
  if (z == 0 && bx == 16 && by == 0) {
    for (int i = tid; i < 1536; i += 256)
      bqkv[i] = (i < 512) ? bq1[i] : (i < 1024 ? bk1[i - 512] : bv1[i - 1024]);
    return;
  }
  if (z == 1 && bx == 16 && by == 0) {
    for (int i = tid; i < 1536; i += 256)
      bca[i] = (i < 512) ? bq2[i] : (i < 1024 ? bk2[i - 512] : bv2[i - 1024]);
    return;
  }
  const float* src; u16* dst; int K, N;
  switch (z) {
    case 0: src = s0; dst = d0; K = 512; N = 512; break;
    case 1: src = s1; dst = d1; K = 512; N = 512; break;
    case 2: src = s2; dst = d2; K = 512; N = 512; break;
    case 3: src = s3; dst = d3; K = 512; N = 512; break;
    case 4: src = s4; dst = d4; K = 512; N = 512; break;
    case 5: src = s5; dst = d5; K = 512; N = 512; break;
    case 6: src = s6; dst = d6; K = 512; N = 512; break;
    case 7: src = s7; dst = d7; K = 512; N = 512; break;
    case 8: src = s8; dst = d8; K = 512; N = 2048; break;
    default: src = s9; dst = d9; K = 2048; N = 512; break;
  }
  int ntl, ktl;
  if (z == 9) { ktl = bx; ntl = by; } else { ntl = bx; ktl = by; }
  if (ntl * 32 >= N || ktl * 32 >= K) return;
  __shared__ float t[32][33];
  int tx = tid & 31, ty = tid >> 5;
  int n0 = ntl * 32, k0 = ktl * 32;
#pragma unroll
  for (int i = 0; i < 4; i++)
    t[ty + i * 8][tx] = src[(size_t)(k0 + ty + i * 8) * N + n0 + tx];
  __syncthreads();
#pragma unroll
  for (int i = 0; i < 4; i++)
    dst[(size_t)(n0 + ty + i * 8) * K + k0 + tx] = f2b(t[tx][ty + i * 8]);
}

// ---- bf16 GEMM: BK=64, counted-vmcnt 2-barrier pipeline, global_load_lds ----
// C[M,Nd] = A[M,K] @ Bt[Nd,K]^T + bias (+res,+gelu). BMxBN tile, 4 waves (2x2).
// SPLITN (decoder CA projections): N-panels <512 read A (x1b) -> outb [.,512];
// panels >=512 read A2 (encb) -> outb2 [.,1024] at gn-512.
template <int BM, int BN, bool OUTB, bool OUTF, bool RES, bool GELU_, bool SPLITN = false>
__global__ __launch_bounds__(256) void gemm_bt(
    const u16* __restrict__ A, const u16* __restrict__ A2,
    const u16* __restrict__ Bt,
    const float* __restrict__ bias, const float* __restrict__ resid,
    u16* __restrict__ outb, u16* __restrict__ outb2,
    float* __restrict__ outf, int K, int Nd) {
  constexpr int MI = BM / 32;      // per-wave M fragments (wave tile BM/2)
  constexpr int NI = BN / 32;      // per-wave N fragments (wave tile BN/2)
  constexpr int RA = BM / 32;      // A staging gloads/thread
  constexpr int RB = BN / 32;      // B staging gloads/thread
  constexpr int L = RA + RB;       // vmcnt per stage
  __shared__ u16 As[2][BM * 64];
  __shared__ u16 Bs[2][BN * 64];
  int tid = threadIdx.x;
  int lane = tid & 63, w = tid >> 6;
  int g = lane >> 4, li = lane & 15;
  int wr = w >> 1, wc = w & 1;
  int m0 = blockIdx.x * BM, n0 = blockIdx.y * BN;
  const u16* Abase = SPLITN ? (n0 < 512 ? A : A2) : A;
  // staging: chunk c = r*256+tid -> row = c>>3, ch = c&7; LDS lane-linear at c*16B.
  // LDS(row,ch) holds global chunk ch^(row&7)  [involution swizzle]
  int row_s = tid >> 3, ch_s = tid & 7;
  const u16* srcs[L];
  int ldsoff[L];
#pragma unroll
  for (int r = 0; r < L; r++) {
    int rr = (r < RA) ? r : r - RA;
    int row = rr * 32 + row_s;
    int csw = ch_s ^ (row & 7);
    srcs[r] = ((r < RA) ? Abase + (size_t)(m0 + row) * K : Bt + (size_t)(n0 + row) * K) + csw * 8;
    ldsoff[r] = (rr * 256 + tid) * 8;
  }
  f32x4 acc[MI][NI] = {};
  int T = K >> 6;
  auto stage = [&](int t, int buf) {
    int k0 = t << 6;
#pragma unroll
    for (int r = 0; r < RA; r++) gload16(srcs[r] + k0, &As[buf][ldsoff[r]]);
#pragma unroll
    for (int r = RA; r < L; r++) gload16(srcs[r] + k0, &Bs[buf][ldsoff[r]]);
  };
  stage(0, 0);
  stage(1, 1);
  for (int t = 0; t < T; t++) {
    int cur = t & 1;
    if (t == T - 1) wait_vmcnt<0>(); else wait_vmcnt<L>();
    __builtin_amdgcn_s_barrier();
    __builtin_amdgcn_sched_barrier(0);
    bf16x8 af[MI][2], bfr[NI][2];
#pragma unroll
    for (int i = 0; i < MI; i++) {
      int R = wr * (BM / 2) + i * 16 + li;
#pragma unroll
      for (int ks = 0; ks < 2; ks++)
        af[i][ks] = *(const bf16x8*)&As[cur][R * 64 + (((ks * 4 + g) ^ (R & 7)) * 8)];
    }
#pragma unroll
    for (int i = 0; i < NI; i++) {
      int R = wc * (BN / 2) + i * 16 + li;
#pragma unroll
      for (int ks = 0; ks < 2; ks++)
        bfr[i][ks] = *(const bf16x8*)&Bs[cur][R * 64 + (((ks * 4 + g) ^ (R & 7)) * 8)];
    }
#pragma unroll
    for (int mi = 0; mi < MI; mi++)
#pragma unroll
      for (int ni = 0; ni < NI; ni++)
#pragma unroll
        for (int ks = 0; ks < 2; ks++)
          acc[mi][ni] = __builtin_amdgcn_mfma_f32_16x16x32_bf16(af[mi][ks], bfr[ni][ks], acc[mi][ni], 0, 0, 0);
    __builtin_amdgcn_s_barrier();
    if (t + 2 < T) stage(t + 2, cur);
  }
#pragma unroll
  for (int mi = 0; mi < MI; mi++)
#pragma unroll
    for (int ni = 0; ni < NI; ni++) {
      int gn = n0 + wc * (BN / 2) + ni * 16 + li;
      float bv = bias[gn];
#pragma unroll
      for (int r = 0; r < 4; r++) {
        int gm = m0 + wr * (BM / 2) + mi * 16 + g * 4 + r;
        float v = acc[mi][ni][r] + bv;
        if (RES) v += resid[(size_t)gm * Nd + gn];
        if (GELU_) v = 0.5f * v * (1.0f + erff(v * 0.70710678118654752f));
        if (OUTF) outf[(size_t)gm * Nd + gn] = v;
        if constexpr (SPLITN) {
          if (gn < 512) outb[(size_t)gm * 512 + gn] = f2b(v);
          else outb2[(size_t)gm * 1024 + gn - 512] = f2b(v);
        } else if (OUTB) {
          outb[(size_t)gm * Nd + gn] = f2b(v);
        }
      }
    }
}

// ---------------- flash attention: KVBLK=128, dbuf, exp2-domain, defer-max ----
// grid 512 flat: bh = idx&15, qb-block(64) = idx>>4. 4 waves x 16 q.
// CAUSAL: complement pairing so blocks c and c+256 sum to ~const work.
template <bool CAUSAL>
__global__ __launch_bounds__(256) void attn_fwd(
    const u16* __restrict__ Q, const u16* __restrict__ Kp,
    const u16* __restrict__ Vp, u16* __restrict__ O, int qs, int kvs) {
  __shared__ u16 Ks[2][128 * 64];   // [key][d] rows 64, chunk-swizzled
  __shared__ u16 Vt[2][64 * 128];   // [d][key] rows 128, chunk-swizzled
  __shared__ u16 Ps[4][16 * 128];   // per-wave P [q][key]
  int tid = threadIdx.x;
  int lane = tid & 63, w = tid >> 6;
  int g = lane >> 4, li = lane & 15;
  int idx = blockIdx.x;
  int bh = idx & 15;
  int qbi = idx >> 4;
  if (CAUSAL) qbi = (idx < 256) ? (31 - qbi) : (qbi - 16);  // complement pairing
  int qb = qbi * 64;
  int b = bh >> 3, h = bh & 7;
  const u16* Qh = Q + (size_t)b * SEQ * qs + h * 64;
  const u16* Kh = Kp + (size_t)b * SEQ * kvs + h * 64;
  const u16* Vh = Vp + (size_t)b * SEQ * kvs + h * 64;
  int qrow = qb + w * 16 + li;
  // Q fragment, pre-scaled by log2(e)/sqrt(64) -> softmax in exp2 domain
  bf16x8 qa[2];
#pragma unroll
  for (int ks = 0; ks < 2; ks++) {
    bf16x8 tq = *(const bf16x8*)&Qh[(size_t)qrow * qs + ks * 32 + g * 8];
#pragma unroll
    for (int j = 0; j < 8; j++) tq[j] = (__bf16)((float)tq[j] * 0.18033688011112042f);
    qa[ks] = tq;
  }
  // K staging via global_load_lds: 4 gloads/thread, lane-linear dest
  int kcc = lane & 7;
  const u16* Ksrc[4];
#pragma unroll
  for (int j = 0; j < 4; j++) {
    int row = j * 32 + w * 8 + (lane >> 3);
    int sw = ((j * 4 + w) ^ (lane >> 3)) & 7;
    Ksrc[j] = Kh + (size_t)row * kvs + (kcc ^ sw) * 8;
  }
  size_t kstep = (size_t)128 * kvs;
  // V staging: thread owns keys 4*kq..+3, d-chunk dcv
  int kq = tid & 31, dcv = tid >> 5;
  const u16* Vsrc = Vh + (size_t)(4 * kq) * kvs + dcv * 8;
  uint4 vr[4];
  auto stageK = [&](int t, int buf) {
    size_t o = (size_t)t * kstep;
    u16* dst = &Ks[buf][w * 512];
#pragma unroll
    for (int j = 0; j < 4; j++) gload16(Ksrc[j] + o, dst + j * 2048);
  };
  auto loadV = [&](int t) {
    size_t o = (size_t)t * kstep;
#pragma unroll
    for (int kk = 0; kk < 4; kk++)
      vr[kk] = *(const uint4*)(Vsrc + o + (size_t)kk * kvs);
  };
  auto writeV = [&](int buf) {
    const u16* a0 = (const u16*)&vr[0];
    const u16* a1 = (const u16*)&vr[1];
    const u16* a2 = (const u16*)&vr[2];
    const u16* a3 = (const u16*)&vr[3];
#pragma unroll
    for (int jj = 0; jj < 8; jj++) {
      int d = dcv * 8 + jj;
      int swv = ((d >> 3) ^ d) & 15;
      uint2 pk;
      pk.x = (unsigned)a0[jj] | ((unsigned)a1[jj] << 16);
      pk.y = (unsigned)a2[jj] | ((unsigned)a3[jj] << 16);
      *(uint2*)&Vt[buf][d * 128 + ((kq >> 1) ^ swv) * 8 + 4 * (kq & 1)] = pk;
    }
  };
  int T = CAUSAL ? (qb >> 7) + 1 : SEQ / 128;
  stageK(0, 0);
  loadV(0);
  writeV(0);
  __syncthreads();
  f32x4 o[4] = {};
  float mreg = -1e30f, lreg = 0.f;
  for (int t = 0; t < T; t++) {
    int cur = t & 1;
    if (t + 1 < T) { stageK(t + 1, cur ^ 1); loadV(t + 1); }
    int kv0 = t << 7;
    // S^T = K.Q^T : lane holds S[k = kv0+nt*16+g*4+r][q = li]
    f32x4 S[8] = {};
    __builtin_amdgcn_s_setprio(1);
#pragma unroll
    for (int nt = 0; nt < 8; nt++) {
      int krow = nt * 16 + li;
      int sw = ((krow >> 3) ^ krow) & 7;
#pragma unroll
      for (int ks = 0; ks < 2; ks++) {
        bf16x8 kb = *(const bf16x8*)&Ks[cur][krow * 64 + ((ks * 4 + g) ^ sw) * 8];
        S[nt] = __builtin_amdgcn_mfma_f32_16x16x32_bf16(kb, qa[ks], S[nt], 0, 0, 0);
      }
    }
    __builtin_amdgcn_s_setprio(0);
    if (CAUSAL && (kv0 + 127 > qb + w * 16)) {  // wave-uniform boundary test
#pragma unroll
      for (int nt = 0; nt < 8; nt++) {
        int kb0 = kv0 + nt * 16 + g * 4;
#pragma unroll
        for (int r = 0; r < 4; r++)
          if (kb0 + r > qrow) S[nt][r] = -1e30f;
      }
    }
    f32x4 mx = S[0];
#pragma unroll
    for (int nt = 1; nt < 8; nt++)
#pragma unroll
      for (int r = 0; r < 4; r++) mx[r] = fmaxf(mx[r], S[nt][r]);
    float pm = fmaxf(fmaxf(mx[0], mx[1]), fmaxf(mx[2], mx[3]));
    pm = fmaxf(pm, __shfl_xor(pm, 16, 64));
    pm = fmaxf(pm, __shfl_xor(pm, 32, 64));
    bool need = __any(pm > mreg + 8.0f);  // defer-max: P bounded by 2^8
    float nm = need ? fmaxf(mreg, pm) : mreg;
    f32x4 acc4 = {0.f, 0.f, 0.f, 0.f};
#pragma unroll
    for (int nt = 0; nt < 8; nt++)
#pragma unroll
      for (int r = 0; r < 4; r++) {
        float e = exp2f(S[nt][r] - nm);
        S[nt][r] = e;
        acc4[r] += e;
      }
    float rs = (acc4[0] + acc4[1]) + (acc4[2] + acc4[3]);
    rs += __shfl_xor(rs, 16, 64);
    rs += __shfl_xor(rs, 32, 64);
    if (need) {
      float csc = exp2f(mreg - nm);
      lreg = lreg * csc + rs;
      mreg = nm;
      float cscr[4];
#pragma unroll
      for (int r = 0; r < 4; r++)
        cscr[r] = __shfl(csc, (lane & 48) | (g * 4 + r), 64);
#pragma unroll
      for (int nd = 0; nd < 4; nd++)
#pragma unroll
        for (int r = 0; r < 4; r++) o[nd][r] *= cscr[r];
    } else {
      lreg += rs;
    }
    // P -> per-wave LDS as b64 (bank-balanced)
#pragma unroll
    for (int nt = 0; nt < 8; nt++) {
      int cp = 2 * nt + (g >> 1);
      uint2 pk;
      pk.x = (unsigned)f2b(S[nt][0]) | ((unsigned)f2b(S[nt][1]) << 16);
      pk.y = (unsigned)f2b(S[nt][2]) | ((unsigned)f2b(S[nt][3]) << 16);
      *(uint2*)&Ps[w][li * 128 + ((cp ^ li) * 8) + 4 * (g & 1)] = pk;
    }
    bf16x8 pa[4];
#pragma unroll
    for (int k2 = 0; k2 < 4; k2++)
      pa[k2] = *(const bf16x8*)&Ps[w][li * 128 + (((k2 * 4 + g) ^ li) * 8)];
    __builtin_amdgcn_s_setprio(1);
#pragma unroll
    for (int nd = 0; nd < 4; nd++) {
      int d = nd * 16 + li;
      int swv = ((d >> 3) ^ d) & 15;
#pragma unroll
      for (int k2 = 0; k2 < 4; k2++) {
        bf16x8 vb = *(const bf16x8*)&Vt[cur][d * 128 + (((k2 * 4 + g) ^ swv) * 8)];
        o[nd] = __builtin_amdgcn_mfma_f32_16x16x32_bf16(pa[k2], vb, o[nd], 0, 0, 0);
      }
    }
    __builtin_amdgcn_s_setprio(0);
    if (t + 1 < T) writeV(cur ^ 1);
    __syncthreads();
  }
  float linv = 1.0f / lreg;
  float invr[4];
#pragma unroll
  for (int r = 0; r < 4; r++)
    invr[r] = __shfl(linv, (lane & 48) | (g * 4 + r), 64);
#pragma unroll
  for (int nd = 0; nd < 4; nd++)
#pragma unroll
    for (int r = 0; r < 4; r++)
      O[(size_t)b * SEQ * EMB + (size_t)(qb + w * 16 + g * 4 + r) * EMB + h * 64 + nd * 16 + li] =
          f2b(o[nd][r] * invr[r]);
}

// ---------------- LayerNorm (one wave per 512-row), fp32 + optional bf16 out ----
__global__ __launch_bounds__(256) void ln_fused(
    const float* __restrict__ in, const float* __restrict__ gamma,
    const float* __restrict__ beta, float* __restrict__ outf, u16* __restrict__ outb) {
  int row = blockIdx.x * 4 + (threadIdx.x >> 6);
  int lane = threadIdx.x & 63;
  const float* p = in + (size_t)row * EMB + lane * 8;
  float v[8];
  *(float4*)&v[0] = *(const float4*)p;
  *(float4*)&v[4] = *(const float4*)(p + 4);
  float s = 0.f, q = 0.f;
#pragma unroll
  for (int j = 0; j < 8; j++) { s += v[j]; q += v[j] * v[j]; }
#pragma unroll
  for (int d = 1; d < 64; d <<= 1) {
    s += __shfl_xor(s, d, 64);
    q += __shfl_xor(q, d, 64);
  }
  float mu = s * (1.0f / EMB);
  float var = q * (1.0f / EMB) - mu * mu;
  float rsig = rsqrtf(var + 1e-5f);
  float gg[8], bb[8];
  *(float4*)&gg[0] = *(const float4*)(gamma + lane * 8);
  *(float4*)&gg[4] = *(const float4*)(gamma + lane * 8 + 4);
  *(float4*)&bb[0] = *(const float4*)(beta + lane * 8);
  *(float4*)&bb[4] = *(const float4*)(beta + lane * 8 + 4);
  float o[8];
#pragma unroll
  for (int j = 0; j < 8; j++) o[j] = (v[j] - mu) * rsig * gg[j] + bb[j];
  float* po = outf + (size_t)row * EMB + lane * 8;
  *(float4*)po = *(float4*)&o[0];
  *(float4*)(po + 4) = *(float4*)&o[4];
  if (outb) {
    uint4 u;
    u.x = f2b(o[0]) | ((unsigned)f2b(o[1]) << 16);
    u.y = f2b(o[2]) | ((unsigned)f2b(o[3]) << 16);
    u.z = f2b(o[4]) | ((unsigned)f2b(o[5]) << 16);
    u.w = f2b(o[6]) | ((unsigned)f2b(o[7]) << 16);
    *(uint4*)(outb + (size_t)row * EMB + lane * 8) = u;
  }
}

extern "C" void kernel_launch(void* const* d_in, const int* in_sizes, int n_in,
                              void* d_out, int out_size, void* d_ws, size_t ws_size,
                              hipStream_t stream) {
  const float* x     = (const float*)d_in[0];
  const float* enc   = (const float*)d_in[1];
  const float* sa_wq = (const float*)d_in[2];
  const float* sa_bq = (const float*)d_in[3];
  const float* sa_wk = (const float*)d_in[4];
  const float* sa_bk = (const float*)d_in[5];
  const float* sa_wv = (const float*)d_in[6];
  const float* sa_bv = (const float*)d_in[7];
  const float* sa_wo = (const float*)d_in[8];
  const float* sa_bo = (const float*)d_in[9];
  const float* ca_wq = (const float*)d_in[10];
  const float* ca_bq = (const float*)d_in[11];
  const float* ca_wk = (const float*)d_in[12];
  const float* ca_bk = (const float*)d_in[13];
  const float* ca_wv = (const float*)d_in[14];
  const float* ca_bv = (const float*)d_in[15];
  const float* ca_wo = (const float*)d_in[16];
  const float* ca_bo = (const float*)d_in[17];
  const float* ln1_g = (const float*)d_in[18];
  const float* ln1_b = (const float*)d_in[19];
  const float* ln2_g = (const float*)d_in[20];
  const float* ln2_b = (const float*)d_in[21];
  const float* ln3_g = (const float*)d_in[22];
  const float* ln3_b = (const float*)d_in[23];
  const float* ff_w1 = (const float*)d_in[24];
  const float* ff_b1 = (const float*)d_in[25];
  const float* ff_w2 = (const float*)d_in[26];
  const float* ff_b2 = (const float*)d_in[27];

  char* ws = (char*)d_ws;
  size_t off = 0;
  auto alloc = [&](size_t bytes) {
    void* p = ws + off;
    off = (off + bytes + 255) & ~(size_t)255;
    return p;
  };
  u16* qkvT_sa  = (u16*)alloc((size_t)1536 * EMB * 2);
  u16* oT_sa    = (u16*)alloc((size_t)EMB * EMB * 2);
  u16* qkvT_ca  = (u16*)alloc((size_t)1536 * EMB * 2);
  u16* oT_ca    = (u16*)alloc((size_t)EMB * EMB * 2);
  u16* w1T      = (u16*)alloc((size_t)FF * EMB * 2);
  u16* w2T      = (u16*)alloc((size_t)EMB * FF * 2);
  float* bqkv_sa = (float*)alloc(1536 * 4);
  float* bca     = (float*)alloc(1536 * 4);
  u16* xb    = (u16*)alloc((size_t)MTOT * EMB * 2);
  u16* encb  = (u16*)alloc((size_t)MTOT * EMB * 2);
  u16* qkv   = (u16*)alloc((size_t)MTOT * 1536 * 2);
  u16* attnb = (u16*)alloc((size_t)MTOT * EMB * 2);
  float* t0  = (float*)alloc((size_t)MTOT * EMB * 4);
  float* x1  = (float*)alloc((size_t)MTOT * EMB * 4);
  u16* x1b   = (u16*)alloc((size_t)MTOT * EMB * 2);
  float* x2  = (float*)alloc((size_t)MTOT * EMB * 4);
  u16* x2b   = (u16*)alloc((size_t)MTOT * EMB * 2);
  u16* hbuf  = (u16*)alloc((size_t)MTOT * FF * 2);
  u16* qca  = xb;   // xb dead after SA-QKV gemm
  u16* kvca = qkv;  // qkv dead after SA attention

  prep_all<<<dim3(64, 16, 12), 256, 0, stream>>>(
      sa_wq, sa_wk, sa_wv, sa_wo, ca_wq, ca_wk, ca_wv, ca_wo, ff_w1, ff_w2,
      qkvT_sa, qkvT_sa + 512 * EMB, qkvT_sa + 1024 * EMB, oT_sa, qkvT_ca,
      qkvT_ca + 512 * EMB, qkvT_ca + 1024 * EMB, oT_ca, w1T, w2T,
      x, xb, enc, encb,
      sa_bq, sa_bk, sa_bv, bqkv_sa, ca_bq, ca_bk, ca_bv, bca);

  // ---- self-attention block ----
  gemm_bt<128, 128, true, false, false, false><<<dim3(32, 12), 256, 0, stream>>>(
      xb, nullptr, qkvT_sa, bqkv_sa, nullptr, qkv, nullptr, nullptr, EMB, 1536);
  attn_fwd<true><<<512, 256, 0, stream>>>(qkv, qkv + 512, qkv + 1024, attnb, 1536, 1536);
  gemm_bt<64, 64, false, true, true, false><<<dim3(64, 8), 256, 0, stream>>>(
      attnb, nullptr, oT_sa, sa_bo, x, nullptr, nullptr, t0, EMB, EMB);
  ln_fused<<<1024, 256, 0, stream>>>(t0, ln1_g, ln1_b, x1, x1b);

  // ---- cross-attention block: merged Q + KV projections (SPLITN) ----
  gemm_bt<128, 128, true, false, false, false, true><<<dim3(32, 12), 256, 0, stream>>>(
      x1b, encb, qkvT_ca, bca, nullptr, qca, kvca, nullptr, EMB, 1536);
  attn_fwd<false><<<512, 256, 0, stream>>>(qca, kvca, kvca + 512, attnb, EMB, 1024);
  gemm_bt<64, 64, false, true, true, false><<<dim3(64, 8), 256, 0, stream>>>(
      attnb, nullptr, oT_ca, ca_bo, x1, nullptr, nullptr, t0, EMB, EMB);
  ln_fused<<<1024, 256, 0, stream>>>(t0, ln2_g, ln2_b, x2, x2b);

  // ---- FFN block ----
  gemm_bt<128, 128, true, false, false, true><<<dim3(32, 16), 256, 0, stream>>>(
      x2b, nullptr, w1T, ff_b1, nullptr, hbuf, nullptr, nullptr, EMB, FF);
  gemm_bt<64, 64, false, true, true, false><<<dim3(64, 8), 256, 0, stream>>>(
      hbuf, nullptr, w2T, ff_b2, x2, nullptr, nullptr, t0, FF, EMB);
  ln_fused<<<1024, 256, 0, stream>>>(t0, ln3_g, ln3_b, (float*)d_out, nullptr);
}